// Round 6
// baseline (276.599 us; speedup 1.0000x reference)
//
#include <hip/hip_runtime.h>

typedef __attribute__((ext_vector_type(8))) short bf16x8;
typedef __attribute__((ext_vector_type(4))) short short4v;
typedef __attribute__((ext_vector_type(4))) float f32x4;
typedef __attribute__((ext_vector_type(16))) float f32x16;

#define D_MODEL 1024
#define SEQ 2048
#define BATCH 4
#define NHEAD 16

__device__ __forceinline__ short f2bf(float f) {
  union { float f; unsigned u; } a; a.f = f;
  unsigned r = a.u + 0x7fffu + ((a.u >> 16) & 1u);
  return (short)(r >> 16);
}

__device__ __forceinline__ void async16(const void* g, void* l) {
  typedef const __attribute__((address_space(1))) unsigned GT;
  typedef __attribute__((address_space(3))) unsigned LT;
  __builtin_amdgcn_global_load_lds((GT*)g, (LT*)l, 16, 0, 0);
}

// ------- weight transpose + bf16 convert (all 4 weights in one launch) -------
__global__ void wprep_kernel(const float* __restrict__ W0, const float* __restrict__ W1,
                             const float* __restrict__ W2, const float* __restrict__ W3,
                             short* __restrict__ Wt) {
  __shared__ short t[32][33];
  const int z = blockIdx.z;
  const float* W = (z == 0) ? W0 : (z == 1) ? W1 : (z == 2) ? W2 : W3;
  short* out = Wt + (size_t)z * 1024 * 1024;
  int tx = threadIdx.x, ty = threadIdx.y;
  int n = blockIdx.x * 32 + tx, k = blockIdx.y * 32 + ty;
  t[ty][tx] = f2bf(W[(size_t)k * 1024 + n]);
  __syncthreads();
  int nn = blockIdx.x * 32 + ty, kk = blockIdx.y * 32 + tx;
  out[(size_t)nn * 1024 + kk] = t[tx][ty];
}

// ---------------- f32 -> bf16 elementwise, two tensors in one launch ----------
__global__ void cvt_bf16_kernel(const float* __restrict__ inA, const float* __restrict__ inB,
                                short* __restrict__ outA, short* __restrict__ outB, int n4each) {
  int idx = blockIdx.x * blockDim.x + threadIdx.x;
  int stride = gridDim.x * blockDim.x;
  for (int i = idx; i < 2 * n4each; i += stride) {
    const float* in = (i < n4each) ? inA : inB;
    short* out = (i < n4each) ? outA : outB;
    int j = (i < n4each) ? i : i - n4each;
    float4 v = ((const float4*)in)[j];
    short4v o; o[0] = f2bf(v.x); o[1] = f2bf(v.y); o[2] = f2bf(v.z); o[3] = f2bf(v.w);
    ((short4v*)out)[j] = o;
  }
}

// ---------------- GEMM: C = A(bf16)[M,K] * Bt(bf16)[N,K]^T + bias -------------
// MODE 0: write Cf (f32) and Cb (bf16 row-major, scaled by cbscale).
// MODE 1: Cb only, permuted KT4 tile layout [B][H][S/64][8 d-chunks][64 kv][8].
// MODE 2: Cf = resid + relu(acc + bias)  (f32 only)
// MODE 3: bias per M-row, Cb only, permuted VT4 layout [B][H][S/64][8 kv-chunks][64 d][8].
template<int MODE>
__global__ __launch_bounds__(256)
void gemm_kernel(const short* __restrict__ A, const short* __restrict__ Bt,
                 const float* __restrict__ bias, const float* __restrict__ resid,
                 float* __restrict__ Cf, short* __restrict__ Cb,
                 int M, int N, int K, float cbscale) {
  __shared__ short lA[128 * 64];
  __shared__ short lB[128 * 64];
  const int tid = threadIdx.x;
  const int lane = tid & 63;
  const int wid = tid >> 6;
  const int wr = wid >> 1, wc = wid & 1;
  const int m0 = blockIdx.y * 128, n0 = blockIdx.x * 128;
  const int lr8 = lane >> 3, lc8 = (lane & 7) * 8;
  const int lr16 = lane & 15, lhi = lane >> 4;

  f32x4 acc[4][4];
  const f32x4 zf = {0.f, 0.f, 0.f, 0.f};
#pragma unroll
  for (int i = 0; i < 4; ++i)
#pragma unroll
    for (int j = 0; j < 4; ++j) acc[i][j] = zf;

  for (int k0 = 0; k0 < K; k0 += 64) {
#pragma unroll
    for (int c = 0; c < 4; ++c) {
      int i = wid * 4 + c;
      async16(A  + (size_t)(m0 + 8 * i + lr8) * K + k0 + lc8, (void*)(lA + i * 512));
      async16(Bt + (size_t)(n0 + 8 * i + lr8) * K + k0 + lc8, (void*)(lB + i * 512));
    }
    __syncthreads();
#pragma unroll
    for (int ks = 0; ks < 2; ++ks) {
      bf16x8 af[4], bfr[4];
#pragma unroll
      for (int mi = 0; mi < 4; ++mi)
        af[mi] = *(const bf16x8*)&lA[(wr * 64 + mi * 16 + lr16) * 64 + ks * 32 + lhi * 8];
#pragma unroll
      for (int ni = 0; ni < 4; ++ni)
        bfr[ni] = *(const bf16x8*)&lB[(wc * 64 + ni * 16 + lr16) * 64 + ks * 32 + lhi * 8];
#pragma unroll
      for (int mi = 0; mi < 4; ++mi)
#pragma unroll
        for (int ni = 0; ni < 4; ++ni)
          acc[mi][ni] = __builtin_amdgcn_mfma_f32_16x16x32_bf16(af[mi], bfr[ni], acc[mi][ni], 0, 0, 0);
    }
    __syncthreads();
  }

#pragma unroll
  for (int mi = 0; mi < 4; ++mi) {
#pragma unroll
    for (int ni = 0; ni < 4; ++ni) {
      int col = n0 + wc * 64 + ni * 16 + lr16;
      float bc = (MODE == 3) ? 0.f : bias[col];
#pragma unroll
      for (int r = 0; r < 4; ++r) {
        int row = m0 + wr * 64 + mi * 16 + lhi * 4 + r;
        size_t off = (size_t)row * N + col;
        float v = acc[mi][ni][r] + ((MODE == 3) ? bias[row] : bc);
        if (MODE == 2) v = resid[off] + fmaxf(v, 0.f);
        if (MODE == 0 || MODE == 2) Cf[off] = v;
        if (MODE == 0) Cb[off] = f2bf(v * cbscale);
        if (MODE == 1) {
          // row = b*2048+s (kv position), col = h*64+d
          int bb = row >> 11, s = row & 2047, t = s >> 6, rr = s & 63;
          int h = col >> 6, d = col & 63;
          size_t idx = ((((size_t)(bb * 16 + h) * 32 + t) * 8 + (d >> 3)) * 64 + rr) * 8 + (d & 7);
          Cb[idx] = f2bf(v);
        }
        if (MODE == 3) {
          // row = h*64+dd (v-dim), col = b*2048+s (kv position)
          int h = row >> 6, dd = row & 63;
          int bb = col >> 11, s = col & 2047, t = s >> 6;
          size_t idx = ((((size_t)(bb * 16 + h) * 32 + t) * 8 + ((s & 63) >> 3)) * 64 + dd) * 8 + (s & 7);
          Cb[idx] = f2bf(v);
        }
      }
    }
  }
}

// ---------------- flash attention + residual(q) -------------------------------
// grid: 1024 linear blocks (XCD-swizzled), 256 threads, 32 q-rows per wave.
// Q pre-scaled by (1/32)*log2(e). K/V supplied in chunk-major tile layout:
// per (b,h,kv-tile of 64): [8 chunks][64 rows][8 shorts] (K: row=kv, chunk=d/8;
// V: row=d, chunk=kv/8). All LDS reads lane-contiguous -> conflict-free.
// 32x32x16 MFMA, swapped operands; P via cvt_pk_bf16 + permlane32_swap.
__global__ __launch_bounds__(256)
void attn_kernel(const short* __restrict__ qb, const short* __restrict__ kt4,
                 const short* __restrict__ vt4, const float* __restrict__ qf,
                 float* __restrict__ O1) {
  __shared__ short lK[2][8 * 64 * 8];
  __shared__ short lV[2][8 * 64 * 8];
  const int tid = threadIdx.x;
  const int lane = tid & 63;
  const int wid = tid >> 6;

  const int flat = blockIdx.x;
  const int w = (flat & 7) * 128 + (flat >> 3);
  const int qblk = w & 15, hh = (w >> 4) & 15, b = w >> 8;
  const int q0w = qblk * 128 + wid * 32;   // wave's 32 q-rows

  const int lr32 = lane & 31, lhi32 = lane >> 5;
  const size_t baseB = (size_t)b * SEQ * D_MODEL;

  // Q as B-fragment: col=q (lane&31), k=d = ks*16 + lhi32*8 + j
  bf16x8 qA[4];
#pragma unroll
  for (int ks = 0; ks < 4; ++ks)
    qA[ks] = *(const bf16x8*)&qb[baseB + (size_t)(q0w + lr32) * D_MODEL + hh * 64 + ks * 16 + lhi32 * 8];

  // chunk-major LDS offsets (shorts), lane-contiguous
  int kOff[2][4];   // A-frag K: chunk = ks*2+lhi32, row = cb*32 + lr32
#pragma unroll
  for (int cb = 0; cb < 2; ++cb)
#pragma unroll
    for (int ks = 0; ks < 4; ++ks)
      kOff[cb][ks] = (ks * 2 + lhi32) * 512 + (cb * 32 + lr32) * 8;
  int vOff[2][4];   // A-frag V^T: chunk = cbp*2+lhi32, row = ni*32 + lr32
#pragma unroll
  for (int ni = 0; ni < 2; ++ni)
#pragma unroll
    for (int cbp = 0; cbp < 4; ++cbp)
      vOff[ni][cbp] = (cbp * 2 + lhi32) * 512 + (ni * 32 + lr32) * 8;

  // staging sources: per-(b,h) tile base; tile = 4096 shorts; chunk = 512 shorts
  const int i0 = wid * 2, i1 = wid * 2 + 1;
  const size_t tbase = (size_t)(b * 16 + hh) * 32 * 4096;
  const short* kS0 = kt4 + tbase + i0 * 512 + lane * 8;
  const short* kS1 = kt4 + tbase + i1 * 512 + lane * 8;
  const short* vS0 = vt4 + tbase + i0 * 512 + lane * 8;
  const short* vS1 = vt4 + tbase + i1 * 512 + lane * 8;

  float lsump = 0.f;
  f32x16 accO[2];
#pragma unroll
  for (int ni = 0; ni < 2; ++ni)
#pragma unroll
    for (int r = 0; r < 16; ++r) accO[ni][r] = 0.f;

  const int NT = SEQ / 64;

#define STAGE(T, BUF)                                              \
  do {                                                             \
    size_t toff = (size_t)(T) * 4096;                              \
    async16(kS0 + toff, (void*)(&lK[BUF][i0 * 512]));              \
    async16(kS1 + toff, (void*)(&lK[BUF][i1 * 512]));              \
    async16(vS0 + toff, (void*)(&lV[BUF][i0 * 512]));              \
    async16(vS1 + toff, (void*)(&lV[BUF][i1 * 512]));              \
  } while (0)

  STAGE(0, 0);

  for (int t = 0; t < NT; ++t) {
    __syncthreads();  // tile t staged; all waves done with buf^1 from t-1
    if (t + 1 < NT) STAGE(t + 1, (t + 1) & 1);
    const short* Kb_ = lK[t & 1];
    const short* Vb_ = lV[t & 1];

#pragma unroll
    for (int cb = 0; cb < 2; ++cb) {
      // S^T[kv][q] = sum_d K[kv][d] * Q[q][d]
      f32x16 s;
#pragma unroll
      for (int r = 0; r < 16; ++r) s[r] = 0.f;
#pragma unroll
      for (int ks = 0; ks < 4; ++ks) {
        bf16x8 kf = *(const bf16x8*)&Kb_[kOff[cb][ks]];
        s = __builtin_amdgcn_mfma_f32_32x32x16_bf16(kf, qA[ks], s, 0, 0, 0);
      }

      // p = exp2(s); per-lane partial denominator (all regs share q)
      float p[16];
#pragma unroll
      for (int r = 0; r < 16; ++r) p[r] = __builtin_amdgcn_exp2f(s[r]);
      float ls0 = 0.f, ls1 = 0.f;
#pragma unroll
      for (int r = 0; r < 8; ++r) { ls0 += p[2 * r]; ls1 += p[2 * r + 1]; }
      lsump += ls0 + ls1;

      // pack pairs: wd[g*2+w2] holds kv pair (cb*32 + 8g + 4*lhi32 + 2w2, +1)
      unsigned wd[8];
#pragma unroll
      for (int g = 0; g < 4; ++g)
#pragma unroll
        for (int w2 = 0; w2 < 2; ++w2) {
          unsigned o;
          asm("v_cvt_pk_bf16_f32 %0, %1, %2" : "=v"(o) : "v"(p[4 * g + 2 * w2]), "v"(p[4 * g + 2 * w2 + 1]));
          wd[g * 2 + w2] = o;
        }

      // permlane32_swap builds B-fragment words for PV (kv 16-blocks cbp=2cb+c1)
#pragma unroll
      for (int c1 = 0; c1 < 2; ++c1) {
        unsigned a0 = wd[(2 * c1) * 2 + 0], b0 = wd[(2 * c1 + 1) * 2 + 0];
        unsigned a1 = wd[(2 * c1) * 2 + 1], b1 = wd[(2 * c1 + 1) * 2 + 1];
        asm("v_permlane32_swap_b32 %0, %1" : "+v"(a0), "+v"(b0));
        asm("v_permlane32_swap_b32 %0, %1" : "+v"(a1), "+v"(b1));
        union { unsigned u[4]; bf16x8 v; } pb;
        pb.u[0] = a0; pb.u[1] = a1; pb.u[2] = b0; pb.u[3] = b1;
        const int cbp = 2 * cb + c1;
#pragma unroll
        for (int ni = 0; ni < 2; ++ni) {
          bf16x8 vf = *(const bf16x8*)&Vb_[vOff[ni][cbp]];
          accO[ni] = __builtin_amdgcn_mfma_f32_32x32x16_bf16(vf, pb.v, accO[ni], 0, 0, 0);
        }
      }
    }
  }
#undef STAGE

  // deferred denominator: lanes l and l+32 hold same q
  float tot = lsump + __shfl_xor(lsump, 32);
  float inv = 1.f / tot;

  const int qrow = q0w + lr32;
  const float* qfp = qf + baseB + (size_t)qrow * D_MODEL + hh * 64;
  float* o1p = O1 + baseB + (size_t)qrow * D_MODEL + hh * 64;
#pragma unroll
  for (int ni = 0; ni < 2; ++ni)
#pragma unroll
    for (int g = 0; g < 4; ++g) {
      int col = ni * 32 + 8 * g + 4 * lhi32;
      float4 qv = *(const float4*)&qfp[col];
      float4 ov;
      ov.x = qv.x + accO[ni][4 * g + 0] * inv;
      ov.y = qv.y + accO[ni][4 * g + 1] * inv;
      ov.z = qv.z + accO[ni][4 * g + 2] * inv;
      ov.w = qv.w + accO[ni][4 * g + 3] * inv;
      *(float4*)&o1p[col] = ov;
    }
}

// ---------------- row LayerNorm (D=1024), optional bf16 copy ------------------
template<int WRITE_BF>
__global__ __launch_bounds__(256)
void ln_kernel(const float* __restrict__ X, const float* __restrict__ g,
               const float* __restrict__ be, float* __restrict__ Yf,
               short* __restrict__ Yb) {
  const int tid = threadIdx.x;
  const size_t row = blockIdx.x;
  float4 v = ((const float4*)(X + row * 1024))[tid];
  float s = v.x + v.y + v.z + v.w;
  float s2 = v.x * v.x + v.y * v.y + v.z * v.z + v.w * v.w;
#pragma unroll
  for (int msk = 1; msk < 64; msk <<= 1) { s += __shfl_xor(s, msk); s2 += __shfl_xor(s2, msk); }
  __shared__ float rs[4], rs2[4];
  if ((tid & 63) == 0) { rs[tid >> 6] = s; rs2[tid >> 6] = s2; }
  __syncthreads();
  s = rs[0] + rs[1] + rs[2] + rs[3];
  s2 = rs2[0] + rs2[1] + rs2[2] + rs2[3];
  float mu = s * (1.f / 1024.f);
  float rstd = rsqrtf(s2 * (1.f / 1024.f) - mu * mu + 1e-5f);
  float4 gv = ((const float4*)g)[tid];
  float4 bv = ((const float4*)be)[tid];
  float4 y;
  y.x = (v.x - mu) * rstd * gv.x + bv.x;
  y.y = (v.y - mu) * rstd * gv.y + bv.y;
  y.z = (v.z - mu) * rstd * gv.z + bv.z;
  y.w = (v.w - mu) * rstd * gv.w + bv.w;
  ((float4*)(Yf + row * 1024))[tid] = y;
  if (WRITE_BF) {
    short4v o; o[0] = f2bf(y.x); o[1] = f2bf(y.y); o[2] = f2bf(y.z); o[3] = f2bf(y.w);
    ((short4v*)(Yb + row * 1024))[tid] = o;
  }
}

extern "C" void kernel_launch(void* const* d_in, const int* in_sizes, int n_in,
                              void* d_out, int out_size, void* d_ws, size_t ws_size,
                              hipStream_t stream) {
  const float* Q  = (const float*)d_in[0];
  const float* K  = (const float*)d_in[1];
  const float* Wq = (const float*)d_in[2];
  const float* bq = (const float*)d_in[3];
  const float* Wk = (const float*)d_in[4];
  const float* bk = (const float*)d_in[5];
  const float* Wv = (const float*)d_in[6];
  const float* bv = (const float*)d_in[7];
  const float* Wo = (const float*)d_in[8];
  const float* bo = (const float*)d_in[9];
  const float* g0 = (const float*)d_in[10];
  const float* b0 = (const float*)d_in[11];
  const float* g1 = (const float*)d_in[12];
  const float* b1 = (const float*)d_in[13];

  char* ws = (char*)d_ws;
  const size_t MB = 1024 * 1024;
  short* Wt  = (short*)(ws + 0);         // 4 matrices x 2MB (1M shorts each)
  short* Qb  = (short*)(ws + 8 * MB);    // 16MB
  short* Kb  = (short*)(ws + 24 * MB);   // 16MB
  short* qbp = (short*)(ws + 40 * MB);   // 16MB
  short* kt4 = (short*)(ws + 56 * MB);   // 16MB  K in chunk-major tile layout
  short* Vt4 = (short*)(ws + 72 * MB);   // 16MB  V^T in chunk-major tile layout
  float* qf  = (float*)(ws + 88 * MB);   // 32MB
  float* O1  = (float*)(ws + 8 * MB);    // reuse Qb/Kb (dead after QKV GEMMs)
  float* Xf  = (float*)(ws + 120 * MB);  // 32MB
  short* Xb  = (short*)(ws + 152 * MB);  // 16MB  (total 168MB)
  float* Y   = (float*)d_out;

  const int Mrows = BATCH * SEQ;  // 8192
  const float SCL = 0.03125f * 1.44269504f;  // (1/32) * log2(e), folded into Q

  wprep_kernel<<<dim3(32, 32, 4), dim3(32, 32), 0, stream>>>(Wq, Wk, Wv, Wo, Wt);

  cvt_bf16_kernel<<<2048, 256, 0, stream>>>(Q, K, Qb, Kb, Mrows * 1024 / 4);

  dim3 ggrid(8, 64);
  gemm_kernel<0><<<ggrid, 256, 0, stream>>>(Qb, Wt + 0 * MB, bq, nullptr, qf, qbp, Mrows, 1024, 1024, SCL);
  gemm_kernel<1><<<ggrid, 256, 0, stream>>>(Kb, Wt + 1 * MB, bk, nullptr, nullptr, kt4, Mrows, 1024, 1024, 1.0f);
  // V^T[d][b*S+s] = sum_k Wv[k][d] * K_in[s][k]  (A = Wv^T prepped, Bt = Kb)
  gemm_kernel<3><<<dim3(64, 8), 256, 0, stream>>>(Wt + 2 * MB, Kb, bv, nullptr, nullptr, Vt4, 1024, Mrows, 1024, 1.0f);

  attn_kernel<<<1024, 256, 0, stream>>>(qbp, kt4, Vt4, qf, O1);

  ln_kernel<1><<<Mrows, 256, 0, stream>>>(O1, g0, b0, Xf, Xb);

  gemm_kernel<2><<<ggrid, 256, 0, stream>>>(Xb, Wt + 3 * MB, bo, Xf, Y, nullptr, Mrows, 1024, 1024, 1.0f);

  ln_kernel<0><<<Mrows, 256, 0, stream>>>(Y, g1, b1, Y, nullptr);
}

// Round 7
// 268.451 us; speedup vs baseline: 1.0303x; 1.0303x over previous
//
#include <hip/hip_runtime.h>

typedef __attribute__((ext_vector_type(8))) short bf16x8;
typedef __attribute__((ext_vector_type(4))) short short4v;
typedef __attribute__((ext_vector_type(4))) float f32x4;
typedef __attribute__((ext_vector_type(16))) float f32x16;

#define D_MODEL 1024
#define SEQ 2048
#define BATCH 4
#define NHEAD 16

__device__ __forceinline__ short f2bf(float f) {
  union { float f; unsigned u; } a; a.f = f;
  unsigned r = a.u + 0x7fffu + ((a.u >> 16) & 1u);
  return (short)(r >> 16);
}

__device__ __forceinline__ float bf2f(short s) {
  union { float f; unsigned u; } a; a.u = ((unsigned)(unsigned short)s) << 16;
  return a.f;
}

__device__ __forceinline__ void async16(const void* g, void* l) {
  typedef const __attribute__((address_space(1))) unsigned GT;
  typedef __attribute__((address_space(3))) unsigned LT;
  __builtin_amdgcn_global_load_lds((GT*)g, (LT*)l, 16, 0, 0);
}

// ------- weight transpose + bf16 convert (all 4 weights in one launch) -------
__global__ void wprep_kernel(const float* __restrict__ W0, const float* __restrict__ W1,
                             const float* __restrict__ W2, const float* __restrict__ W3,
                             short* __restrict__ Wt) {
  __shared__ short t[32][33];
  const int z = blockIdx.z;
  const float* W = (z == 0) ? W0 : (z == 1) ? W1 : (z == 2) ? W2 : W3;
  short* out = Wt + (size_t)z * 1024 * 1024;
  int tx = threadIdx.x, ty = threadIdx.y;
  int n = blockIdx.x * 32 + tx, k = blockIdx.y * 32 + ty;
  t[ty][tx] = f2bf(W[(size_t)k * 1024 + n]);
  __syncthreads();
  int nn = blockIdx.x * 32 + ty, kk = blockIdx.y * 32 + tx;
  out[(size_t)nn * 1024 + kk] = t[tx][ty];
}

// ---------------- f32 -> bf16 elementwise, two tensors in one launch ----------
__global__ void cvt_bf16_kernel(const float* __restrict__ inA, const float* __restrict__ inB,
                                short* __restrict__ outA, short* __restrict__ outB, int n4each) {
  int idx = blockIdx.x * blockDim.x + threadIdx.x;
  int stride = gridDim.x * blockDim.x;
  for (int i = idx; i < 2 * n4each; i += stride) {
    const float* in = (i < n4each) ? inA : inB;
    short* out = (i < n4each) ? outA : outB;
    int j = (i < n4each) ? i : i - n4each;
    float4 v = ((const float4*)in)[j];
    short4v o; o[0] = f2bf(v.x); o[1] = f2bf(v.y); o[2] = f2bf(v.z); o[3] = f2bf(v.w);
    ((short4v*)out)[j] = o;
  }
}

// ---- GEMM: C = A(bf16)[M,K] * Bt(bf16)[N,K]^T + bias.  BM=128 BN=256 BK=64 ----
// 512 threads / 8 waves (2Mx4N, 64x64 per wave), double-buffered LDS, 2-phase.
// T2 XOR-swizzle: staged with pre-swizzled global source, reads XOR (row&7)<<3.
// MODE 1: Cb only, permuted KT4 tile layout [B][H][S/64][8 d-chunks][64 kv][8], *cbscale.
// MODE 2: Cf = resid + relu(acc + bias)  (f32 only)
// MODE 3: bias per M-row, Cb only, permuted VT4 layout [B][H][S/64][8 kv-chunks][64 d][8].
// MODE 4: Cb row-major bf16 only.
template<int MODE>
__global__ __launch_bounds__(512)
void gemm_kernel(const short* __restrict__ A, const short* __restrict__ Bt,
                 const float* __restrict__ bias, const float* __restrict__ resid,
                 float* __restrict__ Cf, short* __restrict__ Cb,
                 int M, int N, int K, float cbscale, int nbx) {
  __shared__ short lA[2][128 * 64];
  __shared__ short lB[2][256 * 64];
  const int tid = threadIdx.x;
  const int lane = tid & 63;
  const int wid = tid >> 6;
  const int wr = wid >> 2, wc = wid & 3;

  // bijective XCD swizzle (grid is always 256 = 8 XCDs x 32)
  const int swz = (blockIdx.x & 7) * 32 + (blockIdx.x >> 3);
  const int m0 = (swz / nbx) * 128, n0 = (swz % nbx) * 256;

  const int lr8 = lane >> 3;
  const int lc8s = ((lane & 7) ^ lr8) * 8;  // pre-swizzled source column (shorts)
  const int lr16 = lane & 15, lhi = lane >> 4;
  const int xk = (lr16 & 7) << 3;           // read-side XOR (shorts)

  f32x4 acc[4][4];
  const f32x4 zf = {0.f, 0.f, 0.f, 0.f};
#pragma unroll
  for (int i = 0; i < 4; ++i)
#pragma unroll
    for (int j = 0; j < 4; ++j) acc[i][j] = zf;

  const int NTK = K >> 6;

#define GSTAGE(T, BUF)                                                          \
  do {                                                                          \
    int k0 = (T) * 64;                                                          \
    _Pragma("unroll")                                                           \
    for (int c = 0; c < 2; ++c) {                                               \
      int i = wid * 2 + c;                                                      \
      async16(A + (size_t)(m0 + 8 * i + lr8) * K + k0 + lc8s,                   \
              (void*)(&lA[BUF][i * 512]));                                      \
    }                                                                           \
    _Pragma("unroll")                                                           \
    for (int c = 0; c < 4; ++c) {                                               \
      int i = wid * 4 + c;                                                      \
      async16(Bt + (size_t)(n0 + 8 * i + lr8) * K + k0 + lc8s,                  \
              (void*)(&lB[BUF][i * 512]));                                      \
    }                                                                           \
  } while (0)

  GSTAGE(0, 0);

  for (int t = 0; t < NTK; ++t) {
    __syncthreads();  // tile t staged (vmcnt drained); buf^1 free
    if (t + 1 < NTK) GSTAGE(t + 1, (t + 1) & 1);
    const short* At_ = lA[t & 1];
    const short* Bt_ = lB[t & 1];
#pragma unroll
    for (int ks = 0; ks < 2; ++ks) {
      const int kcol = (ks * 32 + lhi * 8) ^ xk;
      bf16x8 af[4], bfr[4];
#pragma unroll
      for (int mi = 0; mi < 4; ++mi)
        af[mi] = *(const bf16x8*)&At_[(wr * 64 + mi * 16 + lr16) * 64 + kcol];
#pragma unroll
      for (int ni = 0; ni < 4; ++ni)
        bfr[ni] = *(const bf16x8*)&Bt_[(wc * 64 + ni * 16 + lr16) * 64 + kcol];
#pragma unroll
      for (int mi = 0; mi < 4; ++mi)
#pragma unroll
        for (int ni = 0; ni < 4; ++ni)
          acc[mi][ni] = __builtin_amdgcn_mfma_f32_16x16x32_bf16(af[mi], bfr[ni], acc[mi][ni], 0, 0, 0);
    }
  }
#undef GSTAGE

#pragma unroll
  for (int mi = 0; mi < 4; ++mi) {
#pragma unroll
    for (int ni = 0; ni < 4; ++ni) {
      int col = n0 + wc * 64 + ni * 16 + lr16;
      float bc = (MODE == 3) ? 0.f : bias[col];
#pragma unroll
      for (int r = 0; r < 4; ++r) {
        int row = m0 + wr * 64 + mi * 16 + lhi * 4 + r;
        size_t off = (size_t)row * N + col;
        float v = acc[mi][ni][r] + ((MODE == 3) ? bias[row] : bc);
        if (MODE == 2) {
          Cf[off] = resid[off] + fmaxf(v, 0.f);
        }
        if (MODE == 4) Cb[off] = f2bf(v * cbscale);
        if (MODE == 1) {
          // row = b*2048+s (kv position), col = h*64+d
          int bb = row >> 11, s = row & 2047, tt = s >> 6, rr = s & 63;
          int h = col >> 6, d = col & 63;
          size_t idx = ((((size_t)(bb * 16 + h) * 32 + tt) * 8 + (d >> 3)) * 64 + rr) * 8 + (d & 7);
          Cb[idx] = f2bf(v * cbscale);
        }
        if (MODE == 3) {
          // row = h*64+dd (v-dim), col = b*2048+s (kv position)
          int h = row >> 6, dd = row & 63;
          int bb = col >> 11, s = col & 2047, tt = s >> 6;
          size_t idx = ((((size_t)(bb * 16 + h) * 32 + tt) * 8 + ((s & 63) >> 3)) * 64 + dd) * 8 + (s & 7);
          Cb[idx] = f2bf(v);
        }
      }
    }
  }
}

// ---------------- flash attention + residual(q) -------------------------------
// grid: 1024 linear blocks (XCD-swizzled), 256 threads, 32 q-rows per wave.
// K supplied pre-scaled by (1/32)*log2(e) (folded in projection). K/V in
// chunk-major tile layout: per (b,h,kv-tile of 64): [8 chunks][64 rows][8].
// 32x32x16 MFMA, swapped operands; P via cvt_pk_bf16 + permlane32_swap.
// Residual q read from bf16 qb.
__global__ __launch_bounds__(256)
void attn_kernel(const short* __restrict__ qb, const short* __restrict__ kt4,
                 const short* __restrict__ vt4, float* __restrict__ O1) {
  __shared__ short lK[2][8 * 64 * 8];
  __shared__ short lV[2][8 * 64 * 8];
  const int tid = threadIdx.x;
  const int lane = tid & 63;
  const int wid = tid >> 6;

  const int flat = blockIdx.x;
  const int w = (flat & 7) * 128 + (flat >> 3);
  const int qblk = w & 15, hh = (w >> 4) & 15, b = w >> 8;
  const int q0w = qblk * 128 + wid * 32;   // wave's 32 q-rows

  const int lr32 = lane & 31, lhi32 = lane >> 5;
  const size_t baseB = (size_t)b * SEQ * D_MODEL;

  // Q as B-fragment: col=q (lane&31), k=d = ks*16 + lhi32*8 + j
  bf16x8 qA[4];
#pragma unroll
  for (int ks = 0; ks < 4; ++ks)
    qA[ks] = *(const bf16x8*)&qb[baseB + (size_t)(q0w + lr32) * D_MODEL + hh * 64 + ks * 16 + lhi32 * 8];

  // chunk-major LDS offsets (shorts), lane-contiguous
  int kOff[2][4];   // A-frag K: chunk = ks*2+lhi32, row = cb*32 + lr32
#pragma unroll
  for (int cb = 0; cb < 2; ++cb)
#pragma unroll
    for (int ks = 0; ks < 4; ++ks)
      kOff[cb][ks] = (ks * 2 + lhi32) * 512 + (cb * 32 + lr32) * 8;
  int vOff[2][4];   // A-frag V^T: chunk = cbp*2+lhi32, row = ni*32 + lr32
#pragma unroll
  for (int ni = 0; ni < 2; ++ni)
#pragma unroll
    for (int cbp = 0; cbp < 4; ++cbp)
      vOff[ni][cbp] = (cbp * 2 + lhi32) * 512 + (ni * 32 + lr32) * 8;

  // staging sources: per-(b,h) tile base; tile = 4096 shorts; chunk = 512 shorts
  const int i0 = wid * 2, i1 = wid * 2 + 1;
  const size_t tbase = (size_t)(b * 16 + hh) * 32 * 4096;
  const short* kS0 = kt4 + tbase + i0 * 512 + lane * 8;
  const short* kS1 = kt4 + tbase + i1 * 512 + lane * 8;
  const short* vS0 = vt4 + tbase + i0 * 512 + lane * 8;
  const short* vS1 = vt4 + tbase + i1 * 512 + lane * 8;

  float lsump = 0.f;
  f32x16 accO[2];
#pragma unroll
  for (int ni = 0; ni < 2; ++ni)
#pragma unroll
    for (int r = 0; r < 16; ++r) accO[ni][r] = 0.f;

  const int NT = SEQ / 64;

#define STAGE(T, BUF)                                              \
  do {                                                             \
    size_t toff = (size_t)(T) * 4096;                              \
    async16(kS0 + toff, (void*)(&lK[BUF][i0 * 512]));              \
    async16(kS1 + toff, (void*)(&lK[BUF][i1 * 512]));              \
    async16(vS0 + toff, (void*)(&lV[BUF][i0 * 512]));              \
    async16(vS1 + toff, (void*)(&lV[BUF][i1 * 512]));              \
  } while (0)

  STAGE(0, 0);

  for (int t = 0; t < NT; ++t) {
    __syncthreads();  // tile t staged; all waves done with buf^1 from t-1
    if (t + 1 < NT) STAGE(t + 1, (t + 1) & 1);
    const short* Kb_ = lK[t & 1];
    const short* Vb_ = lV[t & 1];

#pragma unroll
    for (int cb = 0; cb < 2; ++cb) {
      // S^T[kv][q] = sum_d K[kv][d] * Q[q][d]
      f32x16 s;
#pragma unroll
      for (int r = 0; r < 16; ++r) s[r] = 0.f;
#pragma unroll
      for (int ks = 0; ks < 4; ++ks) {
        bf16x8 kf = *(const bf16x8*)&Kb_[kOff[cb][ks]];
        s = __builtin_amdgcn_mfma_f32_32x32x16_bf16(kf, qA[ks], s, 0, 0, 0);
      }

      // p = exp2(s); per-lane partial denominator (all regs share q)
      float p[16];
#pragma unroll
      for (int r = 0; r < 16; ++r) p[r] = __builtin_amdgcn_exp2f(s[r]);
      float ls0 = 0.f, ls1 = 0.f;
#pragma unroll
      for (int r = 0; r < 8; ++r) { ls0 += p[2 * r]; ls1 += p[2 * r + 1]; }
      lsump += ls0 + ls1;

      // pack pairs: wd[g*2+w2] holds kv pair (cb*32 + 8g + 4*lhi32 + 2w2, +1)
      unsigned wd[8];
#pragma unroll
      for (int g = 0; g < 4; ++g)
#pragma unroll
        for (int w2 = 0; w2 < 2; ++w2) {
          unsigned o;
          asm("v_cvt_pk_bf16_f32 %0, %1, %2" : "=v"(o) : "v"(p[4 * g + 2 * w2]), "v"(p[4 * g + 2 * w2 + 1]));
          wd[g * 2 + w2] = o;
        }

      // permlane32_swap builds B-fragment words for PV (kv 16-blocks cbp=2cb+c1)
#pragma unroll
      for (int c1 = 0; c1 < 2; ++c1) {
        unsigned a0 = wd[(2 * c1) * 2 + 0], b0 = wd[(2 * c1 + 1) * 2 + 0];
        unsigned a1 = wd[(2 * c1) * 2 + 1], b1 = wd[(2 * c1 + 1) * 2 + 1];
        asm("v_permlane32_swap_b32 %0, %1" : "+v"(a0), "+v"(b0));
        asm("v_permlane32_swap_b32 %0, %1" : "+v"(a1), "+v"(b1));
        union { unsigned u[4]; bf16x8 v; } pb;
        pb.u[0] = a0; pb.u[1] = a1; pb.u[2] = b0; pb.u[3] = b1;
        const int cbp = 2 * cb + c1;
#pragma unroll
        for (int ni = 0; ni < 2; ++ni) {
          bf16x8 vf = *(const bf16x8*)&Vb_[vOff[ni][cbp]];
          accO[ni] = __builtin_amdgcn_mfma_f32_32x32x16_bf16(vf, pb.v, accO[ni], 0, 0, 0);
        }
      }
    }
  }
#undef STAGE

  // deferred denominator: lanes l and l+32 hold same q
  float tot = lsump + __shfl_xor(lsump, 32);
  float inv = 1.f / tot;

  const int qrow = q0w + lr32;
  const short* qbp2 = qb + baseB + (size_t)qrow * D_MODEL + hh * 64;
  float* o1p = O1 + baseB + (size_t)qrow * D_MODEL + hh * 64;
#pragma unroll
  for (int ni = 0; ni < 2; ++ni)
#pragma unroll
    for (int g = 0; g < 4; ++g) {
      int col = ni * 32 + 8 * g + 4 * lhi32;
      short4v qs = *(const short4v*)&qbp2[col];
      float4 ov;
      ov.x = bf2f(qs[0]) + accO[ni][4 * g + 0] * inv;
      ov.y = bf2f(qs[1]) + accO[ni][4 * g + 1] * inv;
      ov.z = bf2f(qs[2]) + accO[ni][4 * g + 2] * inv;
      ov.w = bf2f(qs[3]) + accO[ni][4 * g + 3] * inv;
      *(float4*)&o1p[col] = ov;
    }
}

// ---------------- row LayerNorm (D=1024), optional bf16 copy ------------------
template<int WRITE_BF>
__global__ __launch_bounds__(256)
void ln_kernel(const float* __restrict__ X, const float* __restrict__ g,
               const float* __restrict__ be, float* __restrict__ Yf,
               short* __restrict__ Yb) {
  const int tid = threadIdx.x;
  const size_t row = blockIdx.x;
  float4 v = ((const float4*)(X + row * 1024))[tid];
  float s = v.x + v.y + v.z + v.w;
  float s2 = v.x * v.x + v.y * v.y + v.z * v.z + v.w * v.w;
#pragma unroll
  for (int msk = 1; msk < 64; msk <<= 1) { s += __shfl_xor(s, msk); s2 += __shfl_xor(s2, msk); }
  __shared__ float rs[4], rs2[4];
  if ((tid & 63) == 0) { rs[tid >> 6] = s; rs2[tid >> 6] = s2; }
  __syncthreads();
  s = rs[0] + rs[1] + rs[2] + rs[3];
  s2 = rs2[0] + rs2[1] + rs2[2] + rs2[3];
  float mu = s * (1.f / 1024.f);
  float rstd = rsqrtf(s2 * (1.f / 1024.f) - mu * mu + 1e-5f);
  float4 gv = ((const float4*)g)[tid];
  float4 bv = ((const float4*)be)[tid];
  float4 y;
  y.x = (v.x - mu) * rstd * gv.x + bv.x;
  y.y = (v.y - mu) * rstd * gv.y + bv.y;
  y.z = (v.z - mu) * rstd * gv.z + bv.z;
  y.w = (v.w - mu) * rstd * gv.w + bv.w;
  ((float4*)(Yf + row * 1024))[tid] = y;
  if (WRITE_BF) {
    short4v o; o[0] = f2bf(y.x); o[1] = f2bf(y.y); o[2] = f2bf(y.z); o[3] = f2bf(y.w);
    ((short4v*)(Yb + row * 1024))[tid] = o;
  }
}

extern "C" void kernel_launch(void* const* d_in, const int* in_sizes, int n_in,
                              void* d_out, int out_size, void* d_ws, size_t ws_size,
                              hipStream_t stream) {
  const float* Q  = (const float*)d_in[0];
  const float* K  = (const float*)d_in[1];
  const float* Wq = (const float*)d_in[2];
  const float* bq = (const float*)d_in[3];
  const float* Wk = (const float*)d_in[4];
  const float* bk = (const float*)d_in[5];
  const float* Wv = (const float*)d_in[6];
  const float* bv = (const float*)d_in[7];
  const float* Wo = (const float*)d_in[8];
  const float* bo = (const float*)d_in[9];
  const float* g0 = (const float*)d_in[10];
  const float* b0 = (const float*)d_in[11];
  const float* g1 = (const float*)d_in[12];
  const float* b1 = (const float*)d_in[13];

  char* ws = (char*)d_ws;
  const size_t MB = 1024 * 1024;
  short* Wt  = (short*)(ws + 0);         // 4 matrices x 2MB (1M shorts each)
  short* Qb  = (short*)(ws + 8 * MB);    // 16MB
  short* Kb  = (short*)(ws + 24 * MB);   // 16MB
  short* qbp = (short*)(ws + 40 * MB);   // 16MB  (bf16 Q-proj, unscaled)
  short* kt4 = (short*)(ws + 56 * MB);   // 16MB  K in chunk-major tile layout (*SCL)
  short* Vt4 = (short*)(ws + 72 * MB);   // 16MB  V^T in chunk-major tile layout
  float* O1  = (float*)(ws + 8 * MB);    // reuse Qb/Kb (dead after QKV GEMMs)
  float* Xf  = (float*)(ws + 120 * MB);  // 32MB
  short* Xb  = (short*)(ws + 152 * MB);  // 16MB  (total 168MB)
  float* Y   = (float*)d_out;

  const int Mrows = BATCH * SEQ;  // 8192
  const float SCL = 0.03125f * 1.44269504f;  // (1/32) * log2(e), folded into K

  wprep_kernel<<<dim3(32, 32, 4), dim3(32, 32), 0, stream>>>(Wq, Wk, Wv, Wo, Wt);

  cvt_bf16_kernel<<<2048, 256, 0, stream>>>(Q, K, Qb, Kb, Mrows * 1024 / 4);

  gemm_kernel<4><<<256, 512, 0, stream>>>(Qb, Wt + 0 * MB, bq, nullptr, nullptr, qbp, Mrows, 1024, 1024, 1.0f, 4);
  gemm_kernel<1><<<256, 512, 0, stream>>>(Kb, Wt + 1 * MB, bk, nullptr, nullptr, kt4, Mrows, 1024, 1024, SCL, 4);
  // V^T[d][b*S+s] = sum_k Wv[k][d] * K_in[s][k]  (A = Wv^T prepped, Bt = Kb)
  gemm_kernel<3><<<256, 512, 0, stream>>>(Wt + 2 * MB, Kb, bv, nullptr, nullptr, Vt4, 1024, Mrows, 1024, 1.0f, 32);

  attn_kernel<<<1024, 256, 0, stream>>>(qbp, kt4, Vt4, O1);

  ln_kernel<1><<<Mrows, 256, 0, stream>>>(O1, g0, b0, Xf, Xb);

  gemm_kernel<2><<<256, 512, 0, stream>>>(Xb, Wt + 3 * MB, bo, Xf, Y, nullptr, Mrows, 1024, 1024, 1.0f, 4);

  ln_kernel<0><<<Mrows, 256, 0, stream>>>(Y, g1, b1, Y, nullptr);
}

// Round 8
// 266.451 us; speedup vs baseline: 1.0381x; 1.0075x over previous
//
#include <hip/hip_runtime.h>

typedef __attribute__((ext_vector_type(8))) short bf16x8;
typedef __attribute__((ext_vector_type(4))) short short4v;
typedef __attribute__((ext_vector_type(4))) float f32x4;
typedef __attribute__((ext_vector_type(16))) float f32x16;

#define D_MODEL 1024
#define SEQ 2048
#define BATCH 4
#define NHEAD 16

__device__ __forceinline__ short f2bf(float f) {
  union { float f; unsigned u; } a; a.f = f;
  unsigned r = a.u + 0x7fffu + ((a.u >> 16) & 1u);
  return (short)(r >> 16);
}

__device__ __forceinline__ float bf2f(short s) {
  union { float f; unsigned u; } a; a.u = ((unsigned)(unsigned short)s) << 16;
  return a.f;
}

__device__ __forceinline__ void async16(const void* g, void* l) {
  typedef const __attribute__((address_space(1))) unsigned GT;
  typedef __attribute__((address_space(3))) unsigned LT;
  __builtin_amdgcn_global_load_lds((GT*)g, (LT*)l, 16, 0, 0);
}

// ------- weight transpose + bf16 convert (all 4 weights in one launch) -------
__global__ void wprep_kernel(const float* __restrict__ W0, const float* __restrict__ W1,
                             const float* __restrict__ W2, const float* __restrict__ W3,
                             short* __restrict__ Wt) {
  __shared__ short t[32][33];
  const int z = blockIdx.z;
  const float* W = (z == 0) ? W0 : (z == 1) ? W1 : (z == 2) ? W2 : W3;
  short* out = Wt + (size_t)z * 1024 * 1024;
  int tx = threadIdx.x, ty = threadIdx.y;
  int n = blockIdx.x * 32 + tx, k = blockIdx.y * 32 + ty;
  t[ty][tx] = f2bf(W[(size_t)k * 1024 + n]);
  __syncthreads();
  int nn = blockIdx.x * 32 + ty, kk = blockIdx.y * 32 + tx;
  out[(size_t)nn * 1024 + kk] = t[tx][ty];
}

// ---------------- f32 -> bf16 elementwise, two tensors in one launch ----------
__global__ void cvt_bf16_kernel(const float* __restrict__ inA, const float* __restrict__ inB,
                                short* __restrict__ outA, short* __restrict__ outB, int n4each) {
  int idx = blockIdx.x * blockDim.x + threadIdx.x;
  int stride = gridDim.x * blockDim.x;
  for (int i = idx; i < 2 * n4each; i += stride) {
    const float* in = (i < n4each) ? inA : inB;
    short* out = (i < n4each) ? outA : outB;
    int j = (i < n4each) ? i : i - n4each;
    float4 v = ((const float4*)in)[j];
    short4v o; o[0] = f2bf(v.x); o[1] = f2bf(v.y); o[2] = f2bf(v.z); o[3] = f2bf(v.w);
    ((short4v*)out)[j] = o;
  }
}

// ---- GEMM: C = A(bf16)[M,K] * Bt(bf16)[N,K]^T + bias.  BM=128 BN=256 BK=64 ----
// 512 threads / 8 waves (2Mx4N, 64x64 per wave), double-buffered LDS.
// Counted-vmcnt 2-deep prefetch: stage t+2 after compute of t; wait vmcnt(6)
// (own 6 loads of tile t) + s_barrier; never drain vmcnt mid-loop. T5 setprio.
// T2 XOR-swizzle: staged with pre-swizzled global source, reads XOR (row&7)<<3.
// MODE 1: Cb only, permuted KT4 tile layout [B][H][S/64][8 d-chunks][64 kv][8], *cbscale.
// MODE 2: Cf = resid + relu(acc + bias)  (f32 only)
// MODE 3: bias per M-row, Cb only, permuted VT4 layout [B][H][S/64][8 kv-chunks][64 d][8].
// MODE 4: Cb row-major bf16 only.
template<int MODE>
__global__ __launch_bounds__(512)
void gemm_kernel(const short* __restrict__ A, const short* __restrict__ Bt,
                 const float* __restrict__ bias, const float* __restrict__ resid,
                 float* __restrict__ Cf, short* __restrict__ Cb,
                 int M, int N, int K, float cbscale, int nbx) {
  __shared__ short lA[2][128 * 64];
  __shared__ short lB[2][256 * 64];
  const int tid = threadIdx.x;
  const int lane = tid & 63;
  const int wid = tid >> 6;
  const int wr = wid >> 2, wc = wid & 3;

  // bijective XCD swizzle (grid is always 256 = 8 XCDs x 32)
  const int swz = (blockIdx.x & 7) * 32 + (blockIdx.x >> 3);
  const int m0 = (swz / nbx) * 128, n0 = (swz % nbx) * 256;

  const int lr8 = lane >> 3;
  const int lc8s = ((lane & 7) ^ lr8) * 8;  // pre-swizzled source column (shorts)
  const int lr16 = lane & 15, lhi = lane >> 4;
  const int xk = (lr16 & 7) << 3;           // read-side XOR (shorts)

  f32x4 acc[4][4];
  const f32x4 zf = {0.f, 0.f, 0.f, 0.f};
#pragma unroll
  for (int i = 0; i < 4; ++i)
#pragma unroll
    for (int j = 0; j < 4; ++j) acc[i][j] = zf;

  const int NTK = K >> 6;

#define GSTAGE(T, BUF)                                                          \
  do {                                                                          \
    int k0 = (T) * 64;                                                          \
    _Pragma("unroll")                                                           \
    for (int c = 0; c < 2; ++c) {                                               \
      int i = wid * 2 + c;                                                      \
      async16(A + (size_t)(m0 + 8 * i + lr8) * K + k0 + lc8s,                   \
              (void*)(&lA[BUF][i * 512]));                                      \
    }                                                                           \
    _Pragma("unroll")                                                           \
    for (int c = 0; c < 4; ++c) {                                               \
      int i = wid * 4 + c;                                                      \
      async16(Bt + (size_t)(n0 + 8 * i + lr8) * K + k0 + lc8s,                  \
              (void*)(&lB[BUF][i * 512]));                                      \
    }                                                                           \
  } while (0)

  GSTAGE(0, 0);
  GSTAGE(1, 1);

  for (int t = 0; t < NTK; ++t) {
    if (t + 1 < NTK) asm volatile("s_waitcnt vmcnt(6)" ::: "memory");
    else             asm volatile("s_waitcnt vmcnt(0)" ::: "memory");
    __builtin_amdgcn_s_barrier();   // all waves' tile-t loads landed
    const short* At_ = lA[t & 1];
    const short* Bt_ = lB[t & 1];
#pragma unroll
    for (int ks = 0; ks < 2; ++ks) {
      const int kcol = (ks * 32 + lhi * 8) ^ xk;
      bf16x8 af[4], bfr[4];
#pragma unroll
      for (int mi = 0; mi < 4; ++mi)
        af[mi] = *(const bf16x8*)&At_[(wr * 64 + mi * 16 + lr16) * 64 + kcol];
#pragma unroll
      for (int ni = 0; ni < 4; ++ni)
        bfr[ni] = *(const bf16x8*)&Bt_[(wc * 64 + ni * 16 + lr16) * 64 + kcol];
      __builtin_amdgcn_s_setprio(1);
#pragma unroll
      for (int mi = 0; mi < 4; ++mi)
#pragma unroll
        for (int ni = 0; ni < 4; ++ni)
          acc[mi][ni] = __builtin_amdgcn_mfma_f32_16x16x32_bf16(af[mi], bfr[ni], acc[mi][ni], 0, 0, 0);
      __builtin_amdgcn_s_setprio(0);
    }
    __builtin_amdgcn_s_barrier();   // all waves done reading buf[t&1]
    if (t + 2 < NTK) GSTAGE(t + 2, t & 1);
  }
#undef GSTAGE

#pragma unroll
  for (int mi = 0; mi < 4; ++mi) {
#pragma unroll
    for (int ni = 0; ni < 4; ++ni) {
      int col = n0 + wc * 64 + ni * 16 + lr16;
      float bc = (MODE == 3) ? 0.f : bias[col];
#pragma unroll
      for (int r = 0; r < 4; ++r) {
        int row = m0 + wr * 64 + mi * 16 + lhi * 4 + r;
        size_t off = (size_t)row * N + col;
        float v = acc[mi][ni][r] + ((MODE == 3) ? bias[row] : bc);
        if (MODE == 2) {
          Cf[off] = resid[off] + fmaxf(v, 0.f);
        }
        if (MODE == 4) Cb[off] = f2bf(v * cbscale);
        if (MODE == 1) {
          // row = b*2048+s (kv position), col = h*64+d
          int bb = row >> 11, s = row & 2047, tt = s >> 6, rr = s & 63;
          int h = col >> 6, d = col & 63;
          size_t idx = ((((size_t)(bb * 16 + h) * 32 + tt) * 8 + (d >> 3)) * 64 + rr) * 8 + (d & 7);
          Cb[idx] = f2bf(v * cbscale);
        }
        if (MODE == 3) {
          // row = h*64+dd (v-dim), col = b*2048+s (kv position)
          int h = row >> 6, dd = row & 63;
          int bb = col >> 11, s = col & 2047, tt = s >> 6;
          size_t idx = ((((size_t)(bb * 16 + h) * 32 + tt) * 8 + ((s & 63) >> 3)) * 64 + dd) * 8 + (s & 7);
          Cb[idx] = f2bf(v);
        }
      }
    }
  }
}

// ---------------- flash attention + residual(q) -------------------------------
// grid: 1024 linear blocks (XCD-swizzled), 256 threads, 32 q-rows per wave.
// K supplied pre-scaled by (1/32)*log2(e) (folded in projection). K/V in
// chunk-major tile layout: per (b,h,kv-tile of 64): [8 chunks][64 rows][8].
// 32x32x16 MFMA, swapped operands; P via cvt_pk_bf16 + permlane32_swap.
// Counted-vmcnt 2-deep prefetch (4 loads/tile/wave), never drains mid-loop.
__global__ __launch_bounds__(256)
void attn_kernel(const short* __restrict__ qb, const short* __restrict__ kt4,
                 const short* __restrict__ vt4, float* __restrict__ O1) {
  __shared__ short lK[2][8 * 64 * 8];
  __shared__ short lV[2][8 * 64 * 8];
  const int tid = threadIdx.x;
  const int lane = tid & 63;
  const int wid = tid >> 6;

  const int flat = blockIdx.x;
  const int w = (flat & 7) * 128 + (flat >> 3);
  const int qblk = w & 15, hh = (w >> 4) & 15, b = w >> 8;
  const int q0w = qblk * 128 + wid * 32;   // wave's 32 q-rows

  const int lr32 = lane & 31, lhi32 = lane >> 5;
  const size_t baseB = (size_t)b * SEQ * D_MODEL;

  // Q as B-fragment: col=q (lane&31), k=d = ks*16 + lhi32*8 + j
  bf16x8 qA[4];
#pragma unroll
  for (int ks = 0; ks < 4; ++ks)
    qA[ks] = *(const bf16x8*)&qb[baseB + (size_t)(q0w + lr32) * D_MODEL + hh * 64 + ks * 16 + lhi32 * 8];

  // chunk-major LDS offsets (shorts), lane-contiguous
  int kOff[2][4];   // A-frag K: chunk = ks*2+lhi32, row = cb*32 + lr32
#pragma unroll
  for (int cb = 0; cb < 2; ++cb)
#pragma unroll
    for (int ks = 0; ks < 4; ++ks)
      kOff[cb][ks] = (ks * 2 + lhi32) * 512 + (cb * 32 + lr32) * 8;
  int vOff[2][4];   // A-frag V^T: chunk = cbp*2+lhi32, row = ni*32 + lr32
#pragma unroll
  for (int ni = 0; ni < 2; ++ni)
#pragma unroll
    for (int cbp = 0; cbp < 4; ++cbp)
      vOff[ni][cbp] = (cbp * 2 + lhi32) * 512 + (ni * 32 + lr32) * 8;

  // staging sources: per-(b,h) tile base; tile = 4096 shorts; chunk = 512 shorts
  const int i0 = wid * 2, i1 = wid * 2 + 1;
  const size_t tbase = (size_t)(b * 16 + hh) * 32 * 4096;
  const short* kS0 = kt4 + tbase + i0 * 512 + lane * 8;
  const short* kS1 = kt4 + tbase + i1 * 512 + lane * 8;
  const short* vS0 = vt4 + tbase + i0 * 512 + lane * 8;
  const short* vS1 = vt4 + tbase + i1 * 512 + lane * 8;

  float lsump = 0.f;
  f32x16 accO[2];
#pragma unroll
  for (int ni = 0; ni < 2; ++ni)
#pragma unroll
    for (int r = 0; r < 16; ++r) accO[ni][r] = 0.f;

  const int NT = SEQ / 64;

#define STAGE(T, BUF)                                              \
  do {                                                             \
    size_t toff = (size_t)(T) * 4096;                              \
    async16(kS0 + toff, (void*)(&lK[BUF][i0 * 512]));              \
    async16(kS1 + toff, (void*)(&lK[BUF][i1 * 512]));              \
    async16(vS0 + toff, (void*)(&lV[BUF][i0 * 512]));              \
    async16(vS1 + toff, (void*)(&lV[BUF][i1 * 512]));              \
  } while (0)

  STAGE(0, 0);
  STAGE(1, 1);

  for (int t = 0; t < NT; ++t) {
    if (t + 1 < NT) asm volatile("s_waitcnt vmcnt(4)" ::: "memory");
    else            asm volatile("s_waitcnt vmcnt(0)" ::: "memory");
    __builtin_amdgcn_s_barrier();   // all waves' tile-t loads landed
    const short* Kb_ = lK[t & 1];
    const short* Vb_ = lV[t & 1];

#pragma unroll
    for (int cb = 0; cb < 2; ++cb) {
      // S^T[kv][q] = sum_d K[kv][d] * Q[q][d]
      f32x16 s;
#pragma unroll
      for (int r = 0; r < 16; ++r) s[r] = 0.f;
#pragma unroll
      for (int ks = 0; ks < 4; ++ks) {
        bf16x8 kf = *(const bf16x8*)&Kb_[kOff[cb][ks]];
        s = __builtin_amdgcn_mfma_f32_32x32x16_bf16(kf, qA[ks], s, 0, 0, 0);
      }

      // p = exp2(s); per-lane partial denominator (all regs share q)
      float p[16];
#pragma unroll
      for (int r = 0; r < 16; ++r) p[r] = __builtin_amdgcn_exp2f(s[r]);
      float ls0 = 0.f, ls1 = 0.f;
#pragma unroll
      for (int r = 0; r < 8; ++r) { ls0 += p[2 * r]; ls1 += p[2 * r + 1]; }
      lsump += ls0 + ls1;

      // pack pairs: wd[g*2+w2] holds kv pair (cb*32 + 8g + 4*lhi32 + 2w2, +1)
      unsigned wd[8];
#pragma unroll
      for (int g = 0; g < 4; ++g)
#pragma unroll
        for (int w2 = 0; w2 < 2; ++w2) {
          unsigned o;
          asm("v_cvt_pk_bf16_f32 %0, %1, %2" : "=v"(o) : "v"(p[4 * g + 2 * w2]), "v"(p[4 * g + 2 * w2 + 1]));
          wd[g * 2 + w2] = o;
        }

      // permlane32_swap builds B-fragment words for PV (kv 16-blocks cbp=2cb+c1)
#pragma unroll
      for (int c1 = 0; c1 < 2; ++c1) {
        unsigned a0 = wd[(2 * c1) * 2 + 0], b0 = wd[(2 * c1 + 1) * 2 + 0];
        unsigned a1 = wd[(2 * c1) * 2 + 1], b1 = wd[(2 * c1 + 1) * 2 + 1];
        asm("v_permlane32_swap_b32 %0, %1" : "+v"(a0), "+v"(b0));
        asm("v_permlane32_swap_b32 %0, %1" : "+v"(a1), "+v"(b1));
        union { unsigned u[4]; bf16x8 v; } pb;
        pb.u[0] = a0; pb.u[1] = a1; pb.u[2] = b0; pb.u[3] = b1;
        const int cbp = 2 * cb + c1;
#pragma unroll
        for (int ni = 0; ni < 2; ++ni) {
          bf16x8 vf = *(const bf16x8*)&Vb_[vOff[ni][cbp]];
          accO[ni] = __builtin_amdgcn_mfma_f32_32x32x16_bf16(vf, pb.v, accO[ni], 0, 0, 0);
        }
      }
    }
    __builtin_amdgcn_s_barrier();   // all waves done reading buf[t&1]
    if (t + 2 < NT) STAGE(t + 2, t & 1);
  }
#undef STAGE

  // deferred denominator: lanes l and l+32 hold same q
  float tot = lsump + __shfl_xor(lsump, 32);
  float inv = 1.f / tot;

  const int qrow = q0w + lr32;
  const short* qbp2 = qb + baseB + (size_t)qrow * D_MODEL + hh * 64;
  float* o1p = O1 + baseB + (size_t)qrow * D_MODEL + hh * 64;
#pragma unroll
  for (int ni = 0; ni < 2; ++ni)
#pragma unroll
    for (int g = 0; g < 4; ++g) {
      int col = ni * 32 + 8 * g + 4 * lhi32;
      short4v qs = *(const short4v*)&qbp2[col];
      float4 ov;
      ov.x = bf2f(qs[0]) + accO[ni][4 * g + 0] * inv;
      ov.y = bf2f(qs[1]) + accO[ni][4 * g + 1] * inv;
      ov.z = bf2f(qs[2]) + accO[ni][4 * g + 2] * inv;
      ov.w = bf2f(qs[3]) + accO[ni][4 * g + 3] * inv;
      *(float4*)&o1p[col] = ov;
    }
}

// ---------------- row LayerNorm (D=1024), optional bf16 copy ------------------
template<int WRITE_BF>
__global__ __launch_bounds__(256)
void ln_kernel(const float* __restrict__ X, const float* __restrict__ g,
               const float* __restrict__ be, float* __restrict__ Yf,
               short* __restrict__ Yb) {
  const int tid = threadIdx.x;
  const size_t row = blockIdx.x;
  float4 v = ((const float4*)(X + row * 1024))[tid];
  float s = v.x + v.y + v.z + v.w;
  float s2 = v.x * v.x + v.y * v.y + v.z * v.z + v.w * v.w;
#pragma unroll
  for (int msk = 1; msk < 64; msk <<= 1) { s += __shfl_xor(s, msk); s2 += __shfl_xor(s2, msk); }
  __shared__ float rs[4], rs2[4];
  if ((tid & 63) == 0) { rs[tid >> 6] = s; rs2[tid >> 6] = s2; }
  __syncthreads();
  s = rs[0] + rs[1] + rs[2] + rs[3];
  s2 = rs2[0] + rs2[1] + rs2[2] + rs2[3];
  float mu = s * (1.f / 1024.f);
  float rstd = rsqrtf(s2 * (1.f / 1024.f) - mu * mu + 1e-5f);
  float4 gv = ((const float4*)g)[tid];
  float4 bv = ((const float4*)be)[tid];
  float4 y;
  y.x = (v.x - mu) * rstd * gv.x + bv.x;
  y.y = (v.y - mu) * rstd * gv.y + bv.y;
  y.z = (v.z - mu) * rstd * gv.z + bv.z;
  y.w = (v.w - mu) * rstd * gv.w + bv.w;
  ((float4*)(Yf + row * 1024))[tid] = y;
  if (WRITE_BF) {
    short4v o; o[0] = f2bf(y.x); o[1] = f2bf(y.y); o[2] = f2bf(y.z); o[3] = f2bf(y.w);
    ((short4v*)(Yb + row * 1024))[tid] = o;
  }
}

extern "C" void kernel_launch(void* const* d_in, const int* in_sizes, int n_in,
                              void* d_out, int out_size, void* d_ws, size_t ws_size,
                              hipStream_t stream) {
  const float* Q  = (const float*)d_in[0];
  const float* K  = (const float*)d_in[1];
  const float* Wq = (const float*)d_in[2];
  const float* bq = (const float*)d_in[3];
  const float* Wk = (const float*)d_in[4];
  const float* bk = (const float*)d_in[5];
  const float* Wv = (const float*)d_in[6];
  const float* bv = (const float*)d_in[7];
  const float* Wo = (const float*)d_in[8];
  const float* bo = (const float*)d_in[9];
  const float* g0 = (const float*)d_in[10];
  const float* b0 = (const float*)d_in[11];
  const float* g1 = (const float*)d_in[12];
  const float* b1 = (const float*)d_in[13];

  char* ws = (char*)d_ws;
  const size_t MB = 1024 * 1024;
  short* Wt  = (short*)(ws + 0);         // 4 matrices x 2MB (1M shorts each)
  short* Qb  = (short*)(ws + 8 * MB);    // 16MB
  short* Kb  = (short*)(ws + 24 * MB);   // 16MB
  short* qbp = (short*)(ws + 40 * MB);   // 16MB  (bf16 Q-proj, unscaled)
  short* kt4 = (short*)(ws + 56 * MB);   // 16MB  K in chunk-major tile layout (*SCL)
  short* Vt4 = (short*)(ws + 72 * MB);   // 16MB  V^T in chunk-major tile layout
  float* O1  = (float*)(ws + 8 * MB);    // reuse Qb/Kb (dead after QKV GEMMs)
  float* Xf  = (float*)(ws + 120 * MB);  // 32MB
  short* Xb  = (short*)(ws + 152 * MB);  // 16MB  (total 168MB)
  float* Y   = (float*)d_out;

  const int Mrows = BATCH * SEQ;  // 8192
  const float SCL = 0.03125f * 1.44269504f;  // (1/32) * log2(e), folded into K

  wprep_kernel<<<dim3(32, 32, 4), dim3(32, 32), 0, stream>>>(Wq, Wk, Wv, Wo, Wt);

  cvt_bf16_kernel<<<2048, 256, 0, stream>>>(Q, K, Qb, Kb, Mrows * 1024 / 4);

  gemm_kernel<4><<<256, 512, 0, stream>>>(Qb, Wt + 0 * MB, bq, nullptr, nullptr, qbp, Mrows, 1024, 1024, 1.0f, 4);
  gemm_kernel<1><<<256, 512, 0, stream>>>(Kb, Wt + 1 * MB, bk, nullptr, nullptr, kt4, Mrows, 1024, 1024, SCL, 4);
  // V^T[d][b*S+s] = sum_k Wv[k][d] * K_in[s][k]  (A = Wv^T prepped, Bt = Kb)
  gemm_kernel<3><<<256, 512, 0, stream>>>(Wt + 2 * MB, Kb, bv, nullptr, nullptr, Vt4, 1024, Mrows, 1024, 1.0f, 32);

  attn_kernel<<<1024, 256, 0, stream>>>(qbp, kt4, Vt4, O1);

  ln_kernel<1><<<Mrows, 256, 0, stream>>>(O1, g0, b0, Xf, Xb);

  gemm_kernel<2><<<256, 512, 0, stream>>>(Xb, Wt + 3 * MB, bo, Xf, Y, nullptr, Mrows, 1024, 1024, 1.0f, 4);

  ln_kernel<0><<<Mrows, 256, 0, stream>>>(Y, g1, b1, Y, nullptr);
}

// Round 9
// 249.084 us; speedup vs baseline: 1.1105x; 1.0697x over previous
//
#include <hip/hip_runtime.h>

typedef __attribute__((ext_vector_type(8))) short bf16x8;
typedef __attribute__((ext_vector_type(4))) short short4v;
typedef __attribute__((ext_vector_type(4))) float f32x4;
typedef __attribute__((ext_vector_type(16))) float f32x16;

#define D_MODEL 1024
#define SEQ 2048
#define BATCH 4
#define NHEAD 16

__device__ __forceinline__ short f2bf(float f) {
  union { float f; unsigned u; } a; a.f = f;
  unsigned r = a.u + 0x7fffu + ((a.u >> 16) & 1u);
  return (short)(r >> 16);
}

__device__ __forceinline__ float bf2f(short s) {
  union { float f; unsigned u; } a; a.u = ((unsigned)(unsigned short)s) << 16;
  return a.f;
}

__device__ __forceinline__ void async16(const void* g, void* l) {
  typedef const __attribute__((address_space(1))) unsigned GT;
  typedef __attribute__((address_space(3))) unsigned LT;
  __builtin_amdgcn_global_load_lds((GT*)g, (LT*)l, 16, 0, 0);
}

// ------- weight transpose + bf16 convert (all 4 weights in one launch) -------
__global__ void wprep_kernel(const float* __restrict__ W0, const float* __restrict__ W1,
                             const float* __restrict__ W2, const float* __restrict__ W3,
                             short* __restrict__ Wt) {
  __shared__ short t[32][33];
  const int z = blockIdx.z;
  const float* W = (z == 0) ? W0 : (z == 1) ? W1 : (z == 2) ? W2 : W3;
  short* out = Wt + (size_t)z * 1024 * 1024;
  int tx = threadIdx.x, ty = threadIdx.y;
  int n = blockIdx.x * 32 + tx, k = blockIdx.y * 32 + ty;
  t[ty][tx] = f2bf(W[(size_t)k * 1024 + n]);
  __syncthreads();
  int nn = blockIdx.x * 32 + ty, kk = blockIdx.y * 32 + tx;
  out[(size_t)nn * 1024 + kk] = t[tx][ty];
}

// ---------------- f32 -> bf16 elementwise, two tensors in one launch ----------
__global__ void cvt_bf16_kernel(const float* __restrict__ inA, const float* __restrict__ inB,
                                short* __restrict__ outA, short* __restrict__ outB, int n4each) {
  int idx = blockIdx.x * blockDim.x + threadIdx.x;
  int stride = gridDim.x * blockDim.x;
  for (int i = idx; i < 2 * n4each; i += stride) {
    const float* in = (i < n4each) ? inA : inB;
    short* out = (i < n4each) ? outA : outB;
    int j = (i < n4each) ? i : i - n4each;
    float4 v = ((const float4*)in)[j];
    short4v o; o[0] = f2bf(v.x); o[1] = f2bf(v.y); o[2] = f2bf(v.z); o[3] = f2bf(v.w);
    ((short4v*)out)[j] = o;
  }
}

// ---- GEMM: C = A(bf16)[M,K] * Bt(bf16)[N,K]^T + bias.  BM=128 BN=256 BK=64 ----
// 512 threads / 8 waves (2Mx4N, 64x64 per wave), double-buffered LDS.
// Counted-vmcnt 2-deep prefetch; T2 XOR-swizzle; T5 setprio.
// MODE 1: Cb only, permuted KT4 tile layout [B][H][S/64][8 d-chunks][64 kv][8], *cbscale.
// MODE 2: Cf = bf16(residb) + relu(acc + bias)  (f32 out, bf16 resid)
// MODE 3: bias per M-row, Cb only, permuted VT4 layout [B][H][S/64][8 kv-chunks][64 d][8].
// MODE 4: Cb row-major bf16 only.
template<int MODE>
__global__ __launch_bounds__(512)
void gemm_kernel(const short* __restrict__ A, const short* __restrict__ Bt,
                 const float* __restrict__ bias, const short* __restrict__ residb,
                 float* __restrict__ Cf, short* __restrict__ Cb,
                 int M, int N, int K, float cbscale, int nbx) {
  __shared__ short lA[2][128 * 64];
  __shared__ short lB[2][256 * 64];
  const int tid = threadIdx.x;
  const int lane = tid & 63;
  const int wid = tid >> 6;
  const int wr = wid >> 2, wc = wid & 3;

  // bijective XCD swizzle (grid is always 256 = 8 XCDs x 32)
  const int swz = (blockIdx.x & 7) * 32 + (blockIdx.x >> 3);
  const int m0 = (swz / nbx) * 128, n0 = (swz % nbx) * 256;

  const int lr8 = lane >> 3;
  const int lc8s = ((lane & 7) ^ lr8) * 8;  // pre-swizzled source column (shorts)
  const int lr16 = lane & 15, lhi = lane >> 4;
  const int xk = (lr16 & 7) << 3;           // read-side XOR (shorts)

  f32x4 acc[4][4];
  const f32x4 zf = {0.f, 0.f, 0.f, 0.f};
#pragma unroll
  for (int i = 0; i < 4; ++i)
#pragma unroll
    for (int j = 0; j < 4; ++j) acc[i][j] = zf;

  const int NTK = K >> 6;

#define GSTAGE(T, BUF)                                                          \
  do {                                                                          \
    int k0 = (T) * 64;                                                          \
    _Pragma("unroll")                                                           \
    for (int c = 0; c < 2; ++c) {                                               \
      int i = wid * 2 + c;                                                      \
      async16(A + (size_t)(m0 + 8 * i + lr8) * K + k0 + lc8s,                   \
              (void*)(&lA[BUF][i * 512]));                                      \
    }                                                                           \
    _Pragma("unroll")                                                           \
    for (int c = 0; c < 4; ++c) {                                               \
      int i = wid * 4 + c;                                                      \
      async16(Bt + (size_t)(n0 + 8 * i + lr8) * K + k0 + lc8s,                  \
              (void*)(&lB[BUF][i * 512]));                                      \
    }                                                                           \
  } while (0)

  GSTAGE(0, 0);
  GSTAGE(1, 1);

  for (int t = 0; t < NTK; ++t) {
    if (t + 1 < NTK) asm volatile("s_waitcnt vmcnt(6)" ::: "memory");
    else             asm volatile("s_waitcnt vmcnt(0)" ::: "memory");
    __builtin_amdgcn_s_barrier();   // all waves' tile-t loads landed
    const short* At_ = lA[t & 1];
    const short* Bt_ = lB[t & 1];
#pragma unroll
    for (int ks = 0; ks < 2; ++ks) {
      const int kcol = (ks * 32 + lhi * 8) ^ xk;
      bf16x8 af[4], bfr[4];
#pragma unroll
      for (int mi = 0; mi < 4; ++mi)
        af[mi] = *(const bf16x8*)&At_[(wr * 64 + mi * 16 + lr16) * 64 + kcol];
#pragma unroll
      for (int ni = 0; ni < 4; ++ni)
        bfr[ni] = *(const bf16x8*)&Bt_[(wc * 64 + ni * 16 + lr16) * 64 + kcol];
      __builtin_amdgcn_s_setprio(1);
#pragma unroll
      for (int mi = 0; mi < 4; ++mi)
#pragma unroll
        for (int ni = 0; ni < 4; ++ni)
          acc[mi][ni] = __builtin_amdgcn_mfma_f32_16x16x32_bf16(af[mi], bfr[ni], acc[mi][ni], 0, 0, 0);
      __builtin_amdgcn_s_setprio(0);
    }
    __builtin_amdgcn_s_barrier();   // all waves done reading buf[t&1]
    if (t + 2 < NTK) GSTAGE(t + 2, t & 1);
  }
#undef GSTAGE

#pragma unroll
  for (int mi = 0; mi < 4; ++mi) {
#pragma unroll
    for (int ni = 0; ni < 4; ++ni) {
      int col = n0 + wc * 64 + ni * 16 + lr16;
      float bc = (MODE == 3) ? 0.f : bias[col];
#pragma unroll
      for (int r = 0; r < 4; ++r) {
        int row = m0 + wr * 64 + mi * 16 + lhi * 4 + r;
        size_t off = (size_t)row * N + col;
        float v = acc[mi][ni][r] + ((MODE == 3) ? bias[row] : bc);
        if (MODE == 2) {
          Cf[off] = bf2f(residb[off]) + fmaxf(v, 0.f);
        }
        if (MODE == 4) Cb[off] = f2bf(v * cbscale);
        if (MODE == 1) {
          // row = b*2048+s (kv position), col = h*64+d
          int bb = row >> 11, s = row & 2047, tt = s >> 6, rr = s & 63;
          int h = col >> 6, d = col & 63;
          size_t idx = ((((size_t)(bb * 16 + h) * 32 + tt) * 8 + (d >> 3)) * 64 + rr) * 8 + (d & 7);
          Cb[idx] = f2bf(v * cbscale);
        }
        if (MODE == 3) {
          // row = h*64+dd (v-dim), col = b*2048+s (kv position)
          int h = row >> 6, dd = row & 63;
          int bb = col >> 11, s = col & 2047, tt = s >> 6;
          size_t idx = ((((size_t)(bb * 16 + h) * 32 + tt) * 8 + ((s & 63) >> 3)) * 64 + dd) * 8 + (s & 7);
          Cb[idx] = f2bf(v);
        }
      }
    }
  }
}

// ---------------- flash attention + residual(q) -------------------------------
// grid: 1024 linear blocks (XCD-swizzled), 256 threads, 32 q-rows per wave.
// K pre-scaled by (1/32)*log2(e). K/V in chunk-major tile layout.
// 32x32x16 MFMA, swapped operands; P via cvt_pk_bf16 + permlane32_swap.
// Denominator via ones-A MFMA (accS row0 = sum_kv P) -- no VALU adds/shuffle.
// Output O1 written bf16.
__global__ __launch_bounds__(256)
void attn_kernel(const short* __restrict__ qb, const short* __restrict__ kt4,
                 const short* __restrict__ vt4, short* __restrict__ O1b) {
  __shared__ short lK[2][8 * 64 * 8];
  __shared__ short lV[2][8 * 64 * 8];
  const int tid = threadIdx.x;
  const int lane = tid & 63;
  const int wid = tid >> 6;

  const int flat = blockIdx.x;
  const int w = (flat & 7) * 128 + (flat >> 3);
  const int qblk = w & 15, hh = (w >> 4) & 15, b = w >> 8;
  const int q0w = qblk * 128 + wid * 32;   // wave's 32 q-rows

  const int lr32 = lane & 31, lhi32 = lane >> 5;
  const size_t baseB = (size_t)b * SEQ * D_MODEL;

  // Q as B-fragment: col=q (lane&31), k=d = ks*16 + lhi32*8 + j
  bf16x8 qA[4];
#pragma unroll
  for (int ks = 0; ks < 4; ++ks)
    qA[ks] = *(const bf16x8*)&qb[baseB + (size_t)(q0w + lr32) * D_MODEL + hh * 64 + ks * 16 + lhi32 * 8];

  // all-ones A-fragment for the denominator MFMA
  bf16x8 onesA;
#pragma unroll
  for (int j = 0; j < 8; ++j) onesA[j] = (short)0x3F80;

  // chunk-major LDS offsets (shorts), lane-contiguous
  int kOff[2][4];   // A-frag K: chunk = ks*2+lhi32, row = cb*32 + lr32
#pragma unroll
  for (int cb = 0; cb < 2; ++cb)
#pragma unroll
    for (int ks = 0; ks < 4; ++ks)
      kOff[cb][ks] = (ks * 2 + lhi32) * 512 + (cb * 32 + lr32) * 8;
  int vOff[2][4];   // A-frag V^T: chunk = cbp*2+lhi32, row = ni*32 + lr32
#pragma unroll
  for (int ni = 0; ni < 2; ++ni)
#pragma unroll
    for (int cbp = 0; cbp < 4; ++cbp)
      vOff[ni][cbp] = (cbp * 2 + lhi32) * 512 + (ni * 32 + lr32) * 8;

  // staging sources: per-(b,h) tile base; tile = 4096 shorts; chunk = 512 shorts
  const int i0 = wid * 2, i1 = wid * 2 + 1;
  const size_t tbase = (size_t)(b * 16 + hh) * 32 * 4096;
  const short* kS0 = kt4 + tbase + i0 * 512 + lane * 8;
  const short* kS1 = kt4 + tbase + i1 * 512 + lane * 8;
  const short* vS0 = vt4 + tbase + i0 * 512 + lane * 8;
  const short* vS1 = vt4 + tbase + i1 * 512 + lane * 8;

  f32x16 accO[2], accS;
#pragma unroll
  for (int r = 0; r < 16; ++r) { accO[0][r] = 0.f; accO[1][r] = 0.f; accS[r] = 0.f; }

  const int NT = SEQ / 64;

#define STAGE(T, BUF)                                              \
  do {                                                             \
    size_t toff = (size_t)(T) * 4096;                              \
    async16(kS0 + toff, (void*)(&lK[BUF][i0 * 512]));              \
    async16(kS1 + toff, (void*)(&lK[BUF][i1 * 512]));              \
    async16(vS0 + toff, (void*)(&lV[BUF][i0 * 512]));              \
    async16(vS1 + toff, (void*)(&lV[BUF][i1 * 512]));              \
  } while (0)

  STAGE(0, 0);
  STAGE(1, 1);

  for (int t = 0; t < NT; ++t) {
    if (t + 1 < NT) asm volatile("s_waitcnt vmcnt(4)" ::: "memory");
    else            asm volatile("s_waitcnt vmcnt(0)" ::: "memory");
    __builtin_amdgcn_s_barrier();   // all waves' tile-t loads landed
    const short* Kb_ = lK[t & 1];
    const short* Vb_ = lV[t & 1];

#pragma unroll
    for (int cb = 0; cb < 2; ++cb) {
      // S^T[kv][q] = sum_d K[kv][d] * Q[q][d]
      f32x16 s;
#pragma unroll
      for (int r = 0; r < 16; ++r) s[r] = 0.f;
#pragma unroll
      for (int ks = 0; ks < 4; ++ks) {
        bf16x8 kf = *(const bf16x8*)&Kb_[kOff[cb][ks]];
        s = __builtin_amdgcn_mfma_f32_32x32x16_bf16(kf, qA[ks], s, 0, 0, 0);
      }

      // p = exp2(s)
      float p[16];
#pragma unroll
      for (int r = 0; r < 16; ++r) p[r] = __builtin_amdgcn_exp2f(s[r]);

      // pack pairs: wd[g*2+w2] holds kv pair (cb*32 + 8g + 4*lhi32 + 2w2, +1)
      unsigned wd[8];
#pragma unroll
      for (int g = 0; g < 4; ++g)
#pragma unroll
        for (int w2 = 0; w2 < 2; ++w2) {
          unsigned o;
          asm("v_cvt_pk_bf16_f32 %0, %1, %2" : "=v"(o) : "v"(p[4 * g + 2 * w2]), "v"(p[4 * g + 2 * w2 + 1]));
          wd[g * 2 + w2] = o;
        }

      // permlane32_swap builds B-fragment words for PV (kv 16-blocks cbp=2cb+c1)
#pragma unroll
      for (int c1 = 0; c1 < 2; ++c1) {
        unsigned a0 = wd[(2 * c1) * 2 + 0], b0 = wd[(2 * c1 + 1) * 2 + 0];
        unsigned a1 = wd[(2 * c1) * 2 + 1], b1 = wd[(2 * c1 + 1) * 2 + 1];
        asm("v_permlane32_swap_b32 %0, %1" : "+v"(a0), "+v"(b0));
        asm("v_permlane32_swap_b32 %0, %1" : "+v"(a1), "+v"(b1));
        union { unsigned u[4]; bf16x8 v; } pb;
        pb.u[0] = a0; pb.u[1] = a1; pb.u[2] = b0; pb.u[3] = b1;
        const int cbp = 2 * cb + c1;
#pragma unroll
        for (int ni = 0; ni < 2; ++ni) {
          bf16x8 vf = *(const bf16x8*)&Vb_[vOff[ni][cbp]];
          accO[ni] = __builtin_amdgcn_mfma_f32_32x32x16_bf16(vf, pb.v, accO[ni], 0, 0, 0);
        }
        accS = __builtin_amdgcn_mfma_f32_32x32x16_bf16(onesA, pb.v, accS, 0, 0, 0);
      }
    }
    __builtin_amdgcn_s_barrier();   // all waves done reading buf[t&1]
    if (t + 2 < NT) STAGE(t + 2, t & 1);
  }
#undef STAGE

  // denominator: every accS row = sum_kv P[kv][q] for q = lane&31
  float inv = 1.f / accS[0];

  const int qrow = q0w + lr32;
  const short* qbp2 = qb + baseB + (size_t)qrow * D_MODEL + hh * 64;
  short* o1p = O1b + baseB + (size_t)qrow * D_MODEL + hh * 64;
#pragma unroll
  for (int ni = 0; ni < 2; ++ni)
#pragma unroll
    for (int g = 0; g < 4; ++g) {
      int col = ni * 32 + 8 * g + 4 * lhi32;
      short4v qs = *(const short4v*)&qbp2[col];
      short4v ov;
#pragma unroll
      for (int j = 0; j < 4; ++j)
        ov[j] = f2bf(bf2f(qs[j]) + accO[ni][4 * g + j] * inv);
      *(short4v*)&o1p[col] = ov;
    }
}

// ---------------- row LayerNorm (D=1024) --------------------------------------
// IN_BF: input bf16 (short*) else f32. OUT_BF: write bf16 Yb only, else f32 Yf.
template<int IN_BF, int OUT_BF>
__global__ __launch_bounds__(256)
void ln_kernel(const void* __restrict__ Xv, const float* __restrict__ g,
               const float* __restrict__ be, float* __restrict__ Yf,
               short* __restrict__ Yb) {
  const int tid = threadIdx.x;
  const size_t row = blockIdx.x;
  float4 v;
  if (IN_BF) {
    short4v xs = ((const short4v*)Xv)[row * 256 + tid];
    v.x = bf2f(xs[0]); v.y = bf2f(xs[1]); v.z = bf2f(xs[2]); v.w = bf2f(xs[3]);
  } else {
    v = ((const float4*)Xv)[row * 256 + tid];
  }
  float s = v.x + v.y + v.z + v.w;
  float s2 = v.x * v.x + v.y * v.y + v.z * v.z + v.w * v.w;
#pragma unroll
  for (int msk = 1; msk < 64; msk <<= 1) { s += __shfl_xor(s, msk); s2 += __shfl_xor(s2, msk); }
  __shared__ float rs[4], rs2[4];
  if ((tid & 63) == 0) { rs[tid >> 6] = s; rs2[tid >> 6] = s2; }
  __syncthreads();
  s = rs[0] + rs[1] + rs[2] + rs[3];
  s2 = rs2[0] + rs2[1] + rs2[2] + rs2[3];
  float mu = s * (1.f / 1024.f);
  float rstd = rsqrtf(s2 * (1.f / 1024.f) - mu * mu + 1e-5f);
  float4 gv = ((const float4*)g)[tid];
  float4 bv = ((const float4*)be)[tid];
  float4 y;
  y.x = (v.x - mu) * rstd * gv.x + bv.x;
  y.y = (v.y - mu) * rstd * gv.y + bv.y;
  y.z = (v.z - mu) * rstd * gv.z + bv.z;
  y.w = (v.w - mu) * rstd * gv.w + bv.w;
  if (OUT_BF) {
    short4v o; o[0] = f2bf(y.x); o[1] = f2bf(y.y); o[2] = f2bf(y.z); o[3] = f2bf(y.w);
    ((short4v*)(Yb + row * 1024))[tid] = o;
  } else {
    ((float4*)(Yf + row * 1024))[tid] = y;
  }
}

extern "C" void kernel_launch(void* const* d_in, const int* in_sizes, int n_in,
                              void* d_out, int out_size, void* d_ws, size_t ws_size,
                              hipStream_t stream) {
  const float* Q  = (const float*)d_in[0];
  const float* K  = (const float*)d_in[1];
  const float* Wq = (const float*)d_in[2];
  const float* bq = (const float*)d_in[3];
  const float* Wk = (const float*)d_in[4];
  const float* bk = (const float*)d_in[5];
  const float* Wv = (const float*)d_in[6];
  const float* bv = (const float*)d_in[7];
  const float* Wo = (const float*)d_in[8];
  const float* bo = (const float*)d_in[9];
  const float* g0 = (const float*)d_in[10];
  const float* b0 = (const float*)d_in[11];
  const float* g1 = (const float*)d_in[12];
  const float* b1 = (const float*)d_in[13];

  char* ws = (char*)d_ws;
  const size_t MB = 1024 * 1024;
  short* Wt  = (short*)(ws + 0);         // 4 matrices x 2MB (1M shorts each)
  short* Qb  = (short*)(ws + 8 * MB);    // 16MB
  short* Kb  = (short*)(ws + 24 * MB);   // 16MB
  short* qbp = (short*)(ws + 40 * MB);   // 16MB  (bf16 Q-proj, unscaled)
  short* kt4 = (short*)(ws + 56 * MB);   // 16MB  K in chunk-major tile layout (*SCL)
  short* Vt4 = (short*)(ws + 72 * MB);   // 16MB  V^T in chunk-major tile layout
  short* O1b = (short*)(ws + 8 * MB);    // 16MB  bf16 attn out (reuse Qb, dead)
  short* Xb  = (short*)(ws + 152 * MB);  // 16MB  bf16 LN1 out
  float* Y   = (float*)d_out;

  const int Mrows = BATCH * SEQ;  // 8192
  const float SCL = 0.03125f * 1.44269504f;  // (1/32) * log2(e), folded into K

  wprep_kernel<<<dim3(32, 32, 4), dim3(32, 32), 0, stream>>>(Wq, Wk, Wv, Wo, Wt);

  cvt_bf16_kernel<<<2048, 256, 0, stream>>>(Q, K, Qb, Kb, Mrows * 1024 / 4);

  gemm_kernel<4><<<256, 512, 0, stream>>>(Qb, Wt + 0 * MB, bq, nullptr, nullptr, qbp, Mrows, 1024, 1024, 1.0f, 4);
  gemm_kernel<1><<<256, 512, 0, stream>>>(Kb, Wt + 1 * MB, bk, nullptr, nullptr, kt4, Mrows, 1024, 1024, SCL, 4);
  // V^T[d][b*S+s] = sum_k Wv[k][d] * K_in[s][k]  (A = Wv^T prepped, Bt = Kb)
  gemm_kernel<3><<<256, 512, 0, stream>>>(Wt + 2 * MB, Kb, bv, nullptr, nullptr, Vt4, 1024, Mrows, 1024, 1.0f, 32);

  attn_kernel<<<1024, 256, 0, stream>>>(qbp, kt4, Vt4, O1b);

  ln_kernel<1, 1><<<Mrows, 256, 0, stream>>>(O1b, g0, b0, nullptr, Xb);

  gemm_kernel<2><<<256, 512, 0, stream>>>(Xb, Wt + 3 * MB, bo, Xb, Y, nullptr, Mrows, 1024, 1024, 1.0f, 4);

  ln_kernel<0, 0><<<Mrows, 256, 0, stream>>>(Y, g1, b1, Y, nullptr);
}

// Round 10
// 234.760 us; speedup vs baseline: 1.1782x; 1.0610x over previous
//
#include <hip/hip_runtime.h>

typedef __attribute__((ext_vector_type(8))) short bf16x8;
typedef __attribute__((ext_vector_type(4))) short short4v;
typedef __attribute__((ext_vector_type(4))) float f32x4;
typedef __attribute__((ext_vector_type(16))) float f32x16;

#define D_MODEL 1024
#define SEQ 2048
#define BATCH 4
#define NHEAD 16

__device__ __forceinline__ short f2bf(float f) {
  union { float f; unsigned u; } a; a.f = f;
  unsigned r = a.u + 0x7fffu + ((a.u >> 16) & 1u);
  return (short)(r >> 16);
}

__device__ __forceinline__ float bf2f(short s) {
  union { float f; unsigned u; } a; a.u = ((unsigned)(unsigned short)s) << 16;
  return a.f;
}

__device__ __forceinline__ void async16(const void* g, void* l) {
  typedef const __attribute__((address_space(1))) unsigned GT;
  typedef __attribute__((address_space(3))) unsigned LT;
  __builtin_amdgcn_global_load_lds((GT*)g, (LT*)l, 16, 0, 0);
}

// ------- weight transpose + bf16 convert (all 4 weights in one launch) -------
__global__ void wprep_kernel(const float* __restrict__ W0, const float* __restrict__ W1,
                             const float* __restrict__ W2, const float* __restrict__ W3,
                             short* __restrict__ Wt) {
  __shared__ short t[32][33];
  const int z = blockIdx.z;
  const float* W = (z == 0) ? W0 : (z == 1) ? W1 : (z == 2) ? W2 : W3;
  short* out = Wt + (size_t)z * 1024 * 1024;
  int tx = threadIdx.x, ty = threadIdx.y;
  int n = blockIdx.x * 32 + tx, k = blockIdx.y * 32 + ty;
  t[ty][tx] = f2bf(W[(size_t)k * 1024 + n]);
  __syncthreads();
  int nn = blockIdx.x * 32 + ty, kk = blockIdx.y * 32 + tx;
  out[(size_t)nn * 1024 + kk] = t[tx][ty];
}

// ---------------- f32 -> bf16 elementwise, two tensors in one launch ----------
__global__ void cvt_bf16_kernel(const float* __restrict__ inA, const float* __restrict__ inB,
                                short* __restrict__ outA, short* __restrict__ outB, int n4each) {
  int idx = blockIdx.x * blockDim.x + threadIdx.x;
  int stride = gridDim.x * blockDim.x;
  for (int i = idx; i < 2 * n4each; i += stride) {
    const float* in = (i < n4each) ? inA : inB;
    short* out = (i < n4each) ? outA : outB;
    int j = (i < n4each) ? i : i - n4each;
    float4 v = ((const float4*)in)[j];
    short4v o; o[0] = f2bf(v.x); o[1] = f2bf(v.y); o[2] = f2bf(v.z); o[3] = f2bf(v.w);
    ((short4v*)out)[j] = o;
  }
}

// ---- GEMM: C = A(bf16)[M,K] * Bt(bf16)[N,K]^T + bias.  BM=128 BN=128 BK=64 ----
// 256 threads / 4 waves (2Mx2N, 64x64 per wave), double-buffered LDS (64KB ->
// 2 blocks/CU for inter-block stall overlap). Counted-vmcnt 2-deep prefetch
// (8 loads/tile/wave -> vmcnt(8)); T2 XOR-swizzle; T5 setprio.
// MODE 1: Cb only, permuted KT4 tile layout [B][H][S/64][8 d-chunks][64 kv][8], *cbscale.
// MODE 2: Cf = bf16(residb) + relu(acc + bias)  (f32 out, bf16 resid)
// MODE 3: bias per M-row, Cb only, permuted VT4 layout [B][H][S/64][8 kv-chunks][64 d][8].
// MODE 4: Cb row-major bf16 only.
template<int MODE>
__global__ __launch_bounds__(256)
void gemm_kernel(const short* __restrict__ A, const short* __restrict__ Bt,
                 const float* __restrict__ bias, const short* __restrict__ residb,
                 float* __restrict__ Cf, short* __restrict__ Cb,
                 int M, int N, int K, float cbscale, int nbx) {
  __shared__ short lA[2][128 * 64];
  __shared__ short lB[2][128 * 64];
  const int tid = threadIdx.x;
  const int lane = tid & 63;
  const int wid = tid >> 6;
  const int wr = wid >> 1, wc = wid & 1;

  // bijective XCD swizzle (grid = 512 = 8 XCDs x 64)
  const int swz = (blockIdx.x & 7) * 64 + (blockIdx.x >> 3);
  const int m0 = (swz / nbx) * 128, n0 = (swz % nbx) * 128;

  const int lr8 = lane >> 3;
  const int lc8s = ((lane & 7) ^ lr8) * 8;  // pre-swizzled source column (shorts)
  const int lr16 = lane & 15, lhi = lane >> 4;
  const int xk = (lr16 & 7) << 3;           // read-side XOR (shorts)

  f32x4 acc[4][4];
  const f32x4 zf = {0.f, 0.f, 0.f, 0.f};
#pragma unroll
  for (int i = 0; i < 4; ++i)
#pragma unroll
    for (int j = 0; j < 4; ++j) acc[i][j] = zf;

  const int NTK = K >> 6;

#define GSTAGE(T, BUF)                                                          \
  do {                                                                          \
    int k0 = (T) * 64;                                                          \
    _Pragma("unroll")                                                           \
    for (int c = 0; c < 4; ++c) {                                               \
      int i = wid * 4 + c;                                                      \
      async16(A + (size_t)(m0 + 8 * i + lr8) * K + k0 + lc8s,                   \
              (void*)(&lA[BUF][i * 512]));                                      \
      async16(Bt + (size_t)(n0 + 8 * i + lr8) * K + k0 + lc8s,                  \
              (void*)(&lB[BUF][i * 512]));                                      \
    }                                                                           \
  } while (0)

  GSTAGE(0, 0);
  GSTAGE(1, 1);

  for (int t = 0; t < NTK; ++t) {
    if (t + 1 < NTK) asm volatile("s_waitcnt vmcnt(8)" ::: "memory");
    else             asm volatile("s_waitcnt vmcnt(0)" ::: "memory");
    __builtin_amdgcn_s_barrier();   // all waves' tile-t loads landed
    const short* At_ = lA[t & 1];
    const short* Bt_ = lB[t & 1];
#pragma unroll
    for (int ks = 0; ks < 2; ++ks) {
      const int kcol = (ks * 32 + lhi * 8) ^ xk;
      bf16x8 af[4], bfr[4];
#pragma unroll
      for (int mi = 0; mi < 4; ++mi)
        af[mi] = *(const bf16x8*)&At_[(wr * 64 + mi * 16 + lr16) * 64 + kcol];
#pragma unroll
      for (int ni = 0; ni < 4; ++ni)
        bfr[ni] = *(const bf16x8*)&Bt_[(wc * 64 + ni * 16 + lr16) * 64 + kcol];
      __builtin_amdgcn_s_setprio(1);
#pragma unroll
      for (int mi = 0; mi < 4; ++mi)
#pragma unroll
        for (int ni = 0; ni < 4; ++ni)
          acc[mi][ni] = __builtin_amdgcn_mfma_f32_16x16x32_bf16(af[mi], bfr[ni], acc[mi][ni], 0, 0, 0);
      __builtin_amdgcn_s_setprio(0);
    }
    __builtin_amdgcn_s_barrier();   // all waves done reading buf[t&1]
    if (t + 2 < NTK) GSTAGE(t + 2, t & 1);
  }
#undef GSTAGE

#pragma unroll
  for (int mi = 0; mi < 4; ++mi) {
#pragma unroll
    for (int ni = 0; ni < 4; ++ni) {
      int col = n0 + wc * 64 + ni * 16 + lr16;
      float bc = (MODE == 3) ? 0.f : bias[col];
#pragma unroll
      for (int r = 0; r < 4; ++r) {
        int row = m0 + wr * 64 + mi * 16 + lhi * 4 + r;
        size_t off = (size_t)row * N + col;
        float v = acc[mi][ni][r] + ((MODE == 3) ? bias[row] : bc);
        if (MODE == 2) {
          Cf[off] = bf2f(residb[off]) + fmaxf(v, 0.f);
        }
        if (MODE == 4) Cb[off] = f2bf(v * cbscale);
        if (MODE == 1) {
          // row = b*2048+s (kv position), col = h*64+d
          int bb = row >> 11, s = row & 2047, tt = s >> 6, rr = s & 63;
          int h = col >> 6, d = col & 63;
          size_t idx = ((((size_t)(bb * 16 + h) * 32 + tt) * 8 + (d >> 3)) * 64 + rr) * 8 + (d & 7);
          Cb[idx] = f2bf(v * cbscale);
        }
        if (MODE == 3) {
          // row = h*64+dd (v-dim), col = b*2048+s (kv position)
          int h = row >> 6, dd = row & 63;
          int bb = col >> 11, s = col & 2047, tt = s >> 6;
          size_t idx = ((((size_t)(bb * 16 + h) * 32 + tt) * 8 + ((s & 63) >> 3)) * 64 + dd) * 8 + (s & 7);
          Cb[idx] = f2bf(v);
        }
      }
    }
  }
}

// ---------------- flash attention + residual(q) -------------------------------
// grid: 1024 linear blocks (XCD-swizzled), 256 threads, 32 q-rows per wave.
// K pre-scaled by (1/32)*log2(e). K/V in chunk-major tile layout.
// 32x32x16 MFMA, swapped operands; P via cvt_pk_bf16 + permlane32_swap.
// Denominator via ones-A MFMA (accS row0 = sum_kv P) -- no VALU adds/shuffle.
// Output O1 written bf16.
__global__ __launch_bounds__(256)
void attn_kernel(const short* __restrict__ qb, const short* __restrict__ kt4,
                 const short* __restrict__ vt4, short* __restrict__ O1b) {
  __shared__ short lK[2][8 * 64 * 8];
  __shared__ short lV[2][8 * 64 * 8];
  const int tid = threadIdx.x;
  const int lane = tid & 63;
  const int wid = tid >> 6;

  const int flat = blockIdx.x;
  const int w = (flat & 7) * 128 + (flat >> 3);
  const int qblk = w & 15, hh = (w >> 4) & 15, b = w >> 8;
  const int q0w = qblk * 128 + wid * 32;   // wave's 32 q-rows

  const int lr32 = lane & 31, lhi32 = lane >> 5;
  const size_t baseB = (size_t)b * SEQ * D_MODEL;

  // Q as B-fragment: col=q (lane&31), k=d = ks*16 + lhi32*8 + j
  bf16x8 qA[4];
#pragma unroll
  for (int ks = 0; ks < 4; ++ks)
    qA[ks] = *(const bf16x8*)&qb[baseB + (size_t)(q0w + lr32) * D_MODEL + hh * 64 + ks * 16 + lhi32 * 8];

  // all-ones A-fragment for the denominator MFMA
  bf16x8 onesA;
#pragma unroll
  for (int j = 0; j < 8; ++j) onesA[j] = (short)0x3F80;

  // chunk-major LDS offsets (shorts), lane-contiguous
  int kOff[2][4];   // A-frag K: chunk = ks*2+lhi32, row = cb*32 + lr32
#pragma unroll
  for (int cb = 0; cb < 2; ++cb)
#pragma unroll
    for (int ks = 0; ks < 4; ++ks)
      kOff[cb][ks] = (ks * 2 + lhi32) * 512 + (cb * 32 + lr32) * 8;
  int vOff[2][4];   // A-frag V^T: chunk = cbp*2+lhi32, row = ni*32 + lr32
#pragma unroll
  for (int ni = 0; ni < 2; ++ni)
#pragma unroll
    for (int cbp = 0; cbp < 4; ++cbp)
      vOff[ni][cbp] = (cbp * 2 + lhi32) * 512 + (ni * 32 + lr32) * 8;

  // staging sources: per-(b,h) tile base; tile = 4096 shorts; chunk = 512 shorts
  const int i0 = wid * 2, i1 = wid * 2 + 1;
  const size_t tbase = (size_t)(b * 16 + hh) * 32 * 4096;
  const short* kS0 = kt4 + tbase + i0 * 512 + lane * 8;
  const short* kS1 = kt4 + tbase + i1 * 512 + lane * 8;
  const short* vS0 = vt4 + tbase + i0 * 512 + lane * 8;
  const short* vS1 = vt4 + tbase + i1 * 512 + lane * 8;

  f32x16 accO[2], accS;
#pragma unroll
  for (int r = 0; r < 16; ++r) { accO[0][r] = 0.f; accO[1][r] = 0.f; accS[r] = 0.f; }

  const int NT = SEQ / 64;

#define STAGE(T, BUF)                                              \
  do {                                                             \
    size_t toff = (size_t)(T) * 4096;                              \
    async16(kS0 + toff, (void*)(&lK[BUF][i0 * 512]));              \
    async16(kS1 + toff, (void*)(&lK[BUF][i1 * 512]));              \
    async16(vS0 + toff, (void*)(&lV[BUF][i0 * 512]));              \
    async16(vS1 + toff, (void*)(&lV[BUF][i1 * 512]));              \
  } while (0)

  STAGE(0, 0);
  STAGE(1, 1);

  for (int t = 0; t < NT; ++t) {
    if (t + 1 < NT) asm volatile("s_waitcnt vmcnt(4)" ::: "memory");
    else            asm volatile("s_waitcnt vmcnt(0)" ::: "memory");
    __builtin_amdgcn_s_barrier();   // all waves' tile-t loads landed
    const short* Kb_ = lK[t & 1];
    const short* Vb_ = lV[t & 1];

#pragma unroll
    for (int cb = 0; cb < 2; ++cb) {
      // S^T[kv][q] = sum_d K[kv][d] * Q[q][d]
      f32x16 s;
#pragma unroll
      for (int r = 0; r < 16; ++r) s[r] = 0.f;
#pragma unroll
      for (int ks = 0; ks < 4; ++ks) {
        bf16x8 kf = *(const bf16x8*)&Kb_[kOff[cb][ks]];
        s = __builtin_amdgcn_mfma_f32_32x32x16_bf16(kf, qA[ks], s, 0, 0, 0);
      }

      // p = exp2(s)
      float p[16];
#pragma unroll
      for (int r = 0; r < 16; ++r) p[r] = __builtin_amdgcn_exp2f(s[r]);

      // pack pairs: wd[g*2+w2] holds kv pair (cb*32 + 8g + 4*lhi32 + 2w2, +1)
      unsigned wd[8];
#pragma unroll
      for (int g = 0; g < 4; ++g)
#pragma unroll
        for (int w2 = 0; w2 < 2; ++w2) {
          unsigned o;
          asm("v_cvt_pk_bf16_f32 %0, %1, %2" : "=v"(o) : "v"(p[4 * g + 2 * w2]), "v"(p[4 * g + 2 * w2 + 1]));
          wd[g * 2 + w2] = o;
        }

      // permlane32_swap builds B-fragment words for PV (kv 16-blocks cbp=2cb+c1)
#pragma unroll
      for (int c1 = 0; c1 < 2; ++c1) {
        unsigned a0 = wd[(2 * c1) * 2 + 0], b0 = wd[(2 * c1 + 1) * 2 + 0];
        unsigned a1 = wd[(2 * c1) * 2 + 1], b1 = wd[(2 * c1 + 1) * 2 + 1];
        asm("v_permlane32_swap_b32 %0, %1" : "+v"(a0), "+v"(b0));
        asm("v_permlane32_swap_b32 %0, %1" : "+v"(a1), "+v"(b1));
        union { unsigned u[4]; bf16x8 v; } pb;
        pb.u[0] = a0; pb.u[1] = a1; pb.u[2] = b0; pb.u[3] = b1;
        const int cbp = 2 * cb + c1;
#pragma unroll
        for (int ni = 0; ni < 2; ++ni) {
          bf16x8 vf = *(const bf16x8*)&Vb_[vOff[ni][cbp]];
          accO[ni] = __builtin_amdgcn_mfma_f32_32x32x16_bf16(vf, pb.v, accO[ni], 0, 0, 0);
        }
        accS = __builtin_amdgcn_mfma_f32_32x32x16_bf16(onesA, pb.v, accS, 0, 0, 0);
      }
    }
    __builtin_amdgcn_s_barrier();   // all waves done reading buf[t&1]
    if (t + 2 < NT) STAGE(t + 2, t & 1);
  }
#undef STAGE

  // denominator: every accS row = sum_kv P[kv][q] for q = lane&31
  float inv = 1.f / accS[0];

  const int qrow = q0w + lr32;
  const short* qbp2 = qb + baseB + (size_t)qrow * D_MODEL + hh * 64;
  short* o1p = O1b + baseB + (size_t)qrow * D_MODEL + hh * 64;
#pragma unroll
  for (int ni = 0; ni < 2; ++ni)
#pragma unroll
    for (int g = 0; g < 4; ++g) {
      int col = ni * 32 + 8 * g + 4 * lhi32;
      short4v qs = *(const short4v*)&qbp2[col];
      short4v ov;
#pragma unroll
      for (int j = 0; j < 4; ++j)
        ov[j] = f2bf(bf2f(qs[j]) + accO[ni][4 * g + j] * inv);
      *(short4v*)&o1p[col] = ov;
    }
}

// ---------------- row LayerNorm (D=1024) --------------------------------------
// IN_BF: input bf16 (short*) else f32. OUT_BF: write bf16 Yb only, else f32 Yf.
template<int IN_BF, int OUT_BF>
__global__ __launch_bounds__(256)
void ln_kernel(const void* __restrict__ Xv, const float* __restrict__ g,
               const float* __restrict__ be, float* __restrict__ Yf,
               short* __restrict__ Yb) {
  const int tid = threadIdx.x;
  const size_t row = blockIdx.x;
  float4 v;
  if (IN_BF) {
    short4v xs = ((const short4v*)Xv)[row * 256 + tid];
    v.x = bf2f(xs[0]); v.y = bf2f(xs[1]); v.z = bf2f(xs[2]); v.w = bf2f(xs[3]);
  } else {
    v = ((const float4*)Xv)[row * 256 + tid];
  }
  float s = v.x + v.y + v.z + v.w;
  float s2 = v.x * v.x + v.y * v.y + v.z * v.z + v.w * v.w;
#pragma unroll
  for (int msk = 1; msk < 64; msk <<= 1) { s += __shfl_xor(s, msk); s2 += __shfl_xor(s2, msk); }
  __shared__ float rs[4], rs2[4];
  if ((tid & 63) == 0) { rs[tid >> 6] = s; rs2[tid >> 6] = s2; }
  __syncthreads();
  s = rs[0] + rs[1] + rs[2] + rs[3];
  s2 = rs2[0] + rs2[1] + rs2[2] + rs2[3];
  float mu = s * (1.f / 1024.f);
  float rstd = rsqrtf(s2 * (1.f / 1024.f) - mu * mu + 1e-5f);
  float4 gv = ((const float4*)g)[tid];
  float4 bv = ((const float4*)be)[tid];
  float4 y;
  y.x = (v.x - mu) * rstd * gv.x + bv.x;
  y.y = (v.y - mu) * rstd * gv.y + bv.y;
  y.z = (v.z - mu) * rstd * gv.z + bv.z;
  y.w = (v.w - mu) * rstd * gv.w + bv.w;
  if (OUT_BF) {
    short4v o; o[0] = f2bf(y.x); o[1] = f2bf(y.y); o[2] = f2bf(y.z); o[3] = f2bf(y.w);
    ((short4v*)(Yb + row * 1024))[tid] = o;
  } else {
    ((float4*)(Yf + row * 1024))[tid] = y;
  }
}

extern "C" void kernel_launch(void* const* d_in, const int* in_sizes, int n_in,
                              void* d_out, int out_size, void* d_ws, size_t ws_size,
                              hipStream_t stream) {
  const float* Q  = (const float*)d_in[0];
  const float* K  = (const float*)d_in[1];
  const float* Wq = (const float*)d_in[2];
  const float* bq = (const float*)d_in[3];
  const float* Wk = (const float*)d_in[4];
  const float* bk = (const float*)d_in[5];
  const float* Wv = (const float*)d_in[6];
  const float* bv = (const float*)d_in[7];
  const float* Wo = (const float*)d_in[8];
  const float* bo = (const float*)d_in[9];
  const float* g0 = (const float*)d_in[10];
  const float* b0 = (const float*)d_in[11];
  const float* g1 = (const float*)d_in[12];
  const float* b1 = (const float*)d_in[13];

  char* ws = (char*)d_ws;
  const size_t MB = 1024 * 1024;
  short* Wt  = (short*)(ws + 0);         // 4 matrices x 2MB (1M shorts each)
  short* Qb  = (short*)(ws + 8 * MB);    // 16MB
  short* Kb  = (short*)(ws + 24 * MB);   // 16MB
  short* qbp = (short*)(ws + 40 * MB);   // 16MB  (bf16 Q-proj, unscaled)
  short* kt4 = (short*)(ws + 56 * MB);   // 16MB  K in chunk-major tile layout (*SCL)
  short* Vt4 = (short*)(ws + 72 * MB);   // 16MB  V^T in chunk-major tile layout
  short* O1b = (short*)(ws + 8 * MB);    // 16MB  bf16 attn out (reuse Qb, dead)
  short* Xb  = (short*)(ws + 152 * MB);  // 16MB  bf16 LN1 out
  float* Y   = (float*)d_out;

  const int Mrows = BATCH * SEQ;  // 8192
  const float SCL = 0.03125f * 1.44269504f;  // (1/32) * log2(e), folded into K

  wprep_kernel<<<dim3(32, 32, 4), dim3(32, 32), 0, stream>>>(Wq, Wk, Wv, Wo, Wt);

  cvt_bf16_kernel<<<2048, 256, 0, stream>>>(Q, K, Qb, Kb, Mrows * 1024 / 4);

  gemm_kernel<4><<<512, 256, 0, stream>>>(Qb, Wt + 0 * MB, bq, nullptr, nullptr, qbp, Mrows, 1024, 1024, 1.0f, 8);
  gemm_kernel<1><<<512, 256, 0, stream>>>(Kb, Wt + 1 * MB, bk, nullptr, nullptr, kt4, Mrows, 1024, 1024, SCL, 8);
  // V^T[d][b*S+s] = sum_k Wv[k][d] * K_in[s][k]  (A = Wv^T prepped, Bt = Kb)
  gemm_kernel<3><<<512, 256, 0, stream>>>(Wt + 2 * MB, Kb, bv, nullptr, nullptr, Vt4, 1024, Mrows, 1024, 1.0f, 64);

  attn_kernel<<<1024, 256, 0, stream>>>(qbp, kt4, Vt4, O1b);

  ln_kernel<1, 1><<<Mrows, 256, 0, stream>>>(O1b, g0, b0, nullptr, Xb);

  gemm_kernel<2><<<512, 256, 0, stream>>>(Xb, Wt + 3 * MB, bo, Xb, Y, nullptr, Mrows, 1024, 1024, 1.0f, 8);

  ln_kernel<0, 0><<<Mrows, 256, 0, stream>>>(Y, g1, b1, Y, nullptr);
}